// Round 2
// baseline (3003.206 us; speedup 1.0000x reference)
//
#include <hip/hip_runtime.h>
#include <math.h>

// Problem constants (fixed instance)
#define LSEQ 2048
#define DM   1024
#define DI   2048
#define E2   4096

// workspace offsets (floats) — total 51,216,416 floats ~= 195 MiB
#define OFF_XZ    ((size_t)0)
#define OFF_XC    ((size_t)33554432)
#define OFF_XDBL  ((size_t)50331648)
#define OFF_FEAT  ((size_t)51118080)
#define OFF_NORM  ((size_t)51183616)
#define OFF_AWS   ((size_t)51183648)
// delta is stored in-place over the x-columns of xz (stride 4096), which are
// dead after feat_kernel + conv_kernel have run.

__device__ __forceinline__ float silu_(float x) { return x / (1.f + __expf(-x)); }
__device__ __forceinline__ float softplus_(float x) {
  return fmaxf(x, 0.f) + log1pf(__expf(-fabsf(x)));
}

// ---------------------------------------------------------------------------
// Generic NT GEMM: C[M,N] = A[M,K] * B[N,K]^T, all row-major, K-contiguous.
// 64x64 tile, BK=16, 256 threads, 4x4 microtile. M assumed multiple of 64,
// K multiple of 16. N guarded. EPI: 0 = none, 1 = softplus(acc + bias[n]).
// ---------------------------------------------------------------------------
template <int EPI>
__global__ __launch_bounds__(256) void gemm_nt(
    const float* __restrict__ A, int lda,
    const float* __restrict__ B, int ldb,
    float* __restrict__ C, int ldc,
    int N, int K, const float* __restrict__ bias)
{
  __shared__ float As[16][68];
  __shared__ float Bs[16][68];
  const int tid = threadIdx.x;
  const int bm = blockIdx.y << 6;
  const int bn = blockIdx.x << 6;
  const int lr = tid >> 2;          // 0..63 : row within tile for loading
  const int lk = (tid & 3) << 2;    // 0,4,8,12 : k offset for loading
  const int tx = tid & 15, ty = tid >> 4;

  float acc[4][4];
#pragma unroll
  for (int i = 0; i < 4; ++i)
#pragma unroll
    for (int j = 0; j < 4; ++j) acc[i][j] = 0.f;

  const float* Ap = A + (size_t)(bm + lr) * lda + lk;
  const float* Bp = B + (size_t)(bn + lr) * ldb + lk;
  const bool bv = (bn + lr) < N;

  for (int k0 = 0; k0 < K; k0 += 16) {
    float4 a4 = *(const float4*)(Ap + k0);
    float4 b4 = bv ? *(const float4*)(Bp + k0) : make_float4(0.f, 0.f, 0.f, 0.f);
    __syncthreads();
    As[lk + 0][lr] = a4.x; As[lk + 1][lr] = a4.y;
    As[lk + 2][lr] = a4.z; As[lk + 3][lr] = a4.w;
    Bs[lk + 0][lr] = b4.x; Bs[lk + 1][lr] = b4.y;
    Bs[lk + 2][lr] = b4.z; Bs[lk + 3][lr] = b4.w;
    __syncthreads();
#pragma unroll
    for (int k = 0; k < 16; ++k) {
      const float4 av = *(const float4*)(&As[k][ty << 2]);
      const float4 bw = *(const float4*)(&Bs[k][tx << 2]);
      float a4r[4] = {av.x, av.y, av.z, av.w};
      float b4r[4] = {bw.x, bw.y, bw.z, bw.w};
#pragma unroll
      for (int i = 0; i < 4; ++i)
#pragma unroll
        for (int j = 0; j < 4; ++j)
          acc[i][j] = fmaf(a4r[i], b4r[j], acc[i][j]);
    }
  }

  const int m = bm + (ty << 2);
  const int n = bn + (tx << 2);
#pragma unroll
  for (int i = 0; i < 4; ++i) {
    float v[4] = {acc[i][0], acc[i][1], acc[i][2], acc[i][3]};
    if (EPI == 1) {
#pragma unroll
      for (int j = 0; j < 4; ++j)
        if (n + j < N) v[j] = softplus_(v[j] + bias[n + j]);
    }
    if (n + 3 < N) {
      *(float4*)(C + (size_t)(m + i) * ldc + n) = make_float4(v[0], v[1], v[2], v[3]);
    } else {
#pragma unroll
      for (int j = 0; j < 4; ++j)
        if (n + j < N) C[(size_t)(m + i) * ldc + n + j] = v[j];
    }
  }
}

// ---------------------------------------------------------------------------
// Channel alignment features: per (frame=b*8+t, channel c) compute
// rfft2(16x16) magnitude band split; features = upper/(total+1e-8).
// 16 channels per block; separable DFT through LDS.
// grid = 32 frames * 128 channel-groups = 4096 blocks.
// ---------------------------------------------------------------------------
__global__ __launch_bounds__(256) void feat_kernel(
    const float* __restrict__ xz, float* __restrict__ features)
{
  __shared__ float xin[256][17];       // [hw][ci]
  __shared__ float Rf[16 * 315];       // [ci]*315 + [kw]*35 + 2h+{0,1}
  __shared__ float tc[16], ts[16];
  __shared__ float part[16][9][2];

  const int tid = threadIdx.x;
  const int frame = blockIdx.x >> 7;   // b*8 + t
  const int cg = blockIdx.x & 127;
  const int b = frame >> 3, t = frame & 7;
  const int c0 = cg << 4;

  if (tid < 16) {
    float ang = 0.39269908169872414f * (float)tid;  // 2*pi*tid/16
    tc[tid] = cosf(ang);
    ts[tid] = sinf(ang);
  }
  const float* xb = xz + ((size_t)(b * LSEQ + t * 256) << 12) + c0;
  for (int i = tid; i < 256 * 16; i += 256) {
    int hw = i >> 4, ci = i & 15;
    xin[hw][ci] = xb[((size_t)hw << 12) + ci];
  }
  __syncthreads();

  // phase 1: row DFT along w. one (ci,h) item per thread.
  {
    const int ci = tid & 15, h = tid >> 4;
    float re[9], im[9];
#pragma unroll
    for (int kw = 0; kw < 9; ++kw) { re[kw] = 0.f; im[kw] = 0.f; }
#pragma unroll
    for (int w = 0; w < 16; ++w) {
      float x = xin[(h << 4) + w][ci];
#pragma unroll
      for (int kw = 0; kw < 9; ++kw) {
        int ph = (kw * w) & 15;
        re[kw] = fmaf(x, tc[ph], re[kw]);
        im[kw] = fmaf(-x, ts[ph], im[kw]);
      }
    }
#pragma unroll
    for (int kw = 0; kw < 9; ++kw) {
      Rf[ci * 315 + kw * 35 + 2 * h]     = re[kw];
      Rf[ci * 315 + kw * 35 + 2 * h + 1] = im[kw];
    }
  }
  __syncthreads();

  // phase 2: column DFT along h + magnitude + band accumulation.
  if (tid < 144) {
    const int ci = tid & 15, kw = tid >> 4;  // kw in 0..8
    float ut = 0.f, tt = 0.f;
    for (int kh = 0; kh < 16; ++kh) {
      float fre = 0.f, fim = 0.f;
#pragma unroll
      for (int h = 0; h < 16; ++h) {
        int ph = (kh * h) & 15;
        float c = tc[ph], s = ts[ph];
        float rr = Rf[ci * 315 + kw * 35 + 2 * h];
        float ri = Rf[ci * 315 + kw * 35 + 2 * h + 1];
        fre += rr * c + ri * s;
        fim += ri * c - rr * s;
      }
      float mag = sqrtf(fre * fre + fim * fim + 1e-8f);
      int sh = (kh + 8) & 15;
      int sw = kw + 4; if (sw >= 9) sw -= 9;
      float dh = (float)(sh - 8) / 16.0f;
      float dw = (float)(sw - 4) / 9.0f;
      tt += mag;
      if (dh * dh + dw * dw >= 0.25f) ut += mag;
    }
    part[ci][kw][0] = ut;
    part[ci][kw][1] = tt;
  }
  __syncthreads();

  if (tid < 16) {
    float ut = 0.f, tt = 0.f;
    for (int kw = 0; kw < 9; ++kw) { ut += part[tid][kw][0]; tt += part[tid][kw][1]; }
    features[frame * DI + c0 + tid] = ut / (tt + 1e-8f);
  }
}

// ---------------------------------------------------------------------------
__global__ __launch_bounds__(256) void norms_kernel(
    const float* __restrict__ feats, float* __restrict__ norms)
{
  __shared__ float red[256];
  const int i = blockIdx.x, tid = threadIdx.x;
  float ss = 0.f;
  for (int d = tid; d < DI; d += 256) {
    float v = feats[i * DI + d];
    ss = fmaf(v, v, ss);
  }
  red[tid] = ss; __syncthreads();
  for (int s = 128; s > 0; s >>= 1) {
    if (tid < s) red[tid] += red[tid + s];
    __syncthreads();
  }
  if (tid == 0) norms[i] = sqrtf(red[0]);
}

// ---------------------------------------------------------------------------
// loss + softmax(mean feat) + attention + A_max/A_min + A output. One block.
// ---------------------------------------------------------------------------
__global__ __launch_bounds__(256) void alpha_kernel(
    const float* __restrict__ feats, const float* __restrict__ norms,
    const float* __restrict__ A_log, float* __restrict__ Aws,
    float* __restrict__ loss_out)
{
  __shared__ float red[256];
  __shared__ float invn[32];
  __shared__ float AM[256][17];
  __shared__ float sAmax[16], sAmin[16];
  const int tid = threadIdx.x;
  if (tid < 32) invn[tid] = 1.f / fmaxf(norms[tid], 1e-12f);
  __syncthreads();

  float md[8]; float gsq = 0.f;
#pragma unroll
  for (int j = 0; j < 8; ++j) {
    const int d = tid + (j << 8);
    float gd = 0.f, sm = 0.f;
    for (int i = 0; i < 32; ++i) {
      float v = feats[(i << 11) + d];
      gd = fmaf(v, invn[i], gd);
      sm += v;
    }
    md[j] = sm * (1.f / 32.f);
    gsq = fmaf(gd, gd, gsq);
  }
  red[tid] = gsq; __syncthreads();
  for (int s = 128; s > 0; s >>= 1) { if (tid < s) red[tid] += red[tid + s]; __syncthreads(); }
  if (tid == 0) loss_out[0] = 1.f - red[0] * (1.f / 1024.f);
  __syncthreads();

  float lm = md[0];
#pragma unroll
  for (int j = 1; j < 8; ++j) lm = fmaxf(lm, md[j]);
  red[tid] = lm; __syncthreads();
  for (int s = 128; s > 0; s >>= 1) { if (tid < s) red[tid] = fmaxf(red[tid], red[tid + s]); __syncthreads(); }
  const float mmax = red[0]; __syncthreads();

  float p[8]; float ps = 0.f;
#pragma unroll
  for (int j = 0; j < 8; ++j) { p[j] = __expf(md[j] - mmax); ps += p[j]; }
  red[tid] = ps; __syncthreads();
  for (int s = 128; s > 0; s >>= 1) { if (tid < s) red[tid] += red[tid + s]; __syncthreads(); }
  const float psum = red[0]; __syncthreads();

  float amaxl[16], aminl[16], rn[8];
#pragma unroll
  for (int n = 0; n < 16; ++n) { amaxl[n] = -1e30f; aminl[n] = 1e30f; }
#pragma unroll
  for (int j = 0; j < 8; ++j) {
    const int d = tid + (j << 8);
    float ss = 0.f;
#pragma unroll
    for (int n = 0; n < 16; ++n) {
      float a = A_log[(d << 4) + n];
      float e = __expf(a);
      ss = fmaf(e, e, ss);
      amaxl[n] = fmaxf(amaxl[n], a);
      aminl[n] = fminf(aminl[n], a);
    }
    rn[j] = sqrtf(ss);
  }
  float rm = rn[0];
#pragma unroll
  for (int j = 1; j < 8; ++j) rm = fmaxf(rm, rn[j]);
  red[tid] = rm; __syncthreads();
  for (int s = 128; s > 0; s >>= 1) { if (tid < s) red[tid] = fmaxf(red[tid], red[tid + s]); __syncthreads(); }
  const float rnmax = red[0]; __syncthreads();

#pragma unroll
  for (int n = 0; n < 16; ++n) AM[tid][n] = amaxl[n];
  __syncthreads();
  if (tid < 16) { float m = -1e30f; for (int i = 0; i < 256; ++i) m = fmaxf(m, AM[i][tid]); sAmax[tid] = m; }
  __syncthreads();
#pragma unroll
  for (int n = 0; n < 16; ++n) AM[tid][n] = aminl[n];
  __syncthreads();
  if (tid < 16) { float m = 1e30f; for (int i = 0; i < 256; ++i) m = fminf(m, AM[i][tid]); sAmin[tid] = m; }
  __syncthreads();

  const float irn = 1.f / (rnmax + 1e-8f);
#pragma unroll
  for (int j = 0; j < 8; ++j) {
    const int d = tid + (j << 8);
    const float att = rn[j] * irn;
    const float f = p[j] / psum;
    const float alpha = fminf(fmaxf(f * (1.f - att), 0.f), 1.f);
#pragma unroll
    for (int n = 0; n < 16; ++n) {
      float a = A_log[(d << 4) + n];
      float fl = sAmax[n] + sAmin[n] - a;
      float an = (1.f - alpha) * a + alpha * fl;
      Aws[(d << 4) + n] = -__expf(an);
    }
  }
}

// ---------------------------------------------------------------------------
// Depthwise causal conv (k=4) + bias + SiLU.  xz (b,l,e4096) -> xc (b,l,e2048)
// ---------------------------------------------------------------------------
__global__ __launch_bounds__(256) void conv_kernel(
    const float* __restrict__ xz, const float* __restrict__ cw,
    const float* __restrict__ cb, float* __restrict__ xc)
{
  const size_t idx = ((size_t)blockIdx.x << 8) + threadIdx.x;  // < 16777216
  const int e = (int)(idx & 2047);
  const int l = (int)((idx >> 11) & 2047);
  const int b = (int)(idx >> 22);
  const float* xr = xz + ((size_t)((b << 11) | l) << 12) + e;
  const float4 w = ((const float4*)cw)[e];
  float acc = cb[e];
  if (l >= 3) acc = fmaf(xr[-3 * 4096], w.x, acc);
  if (l >= 2) acc = fmaf(xr[-2 * 4096], w.y, acc);
  if (l >= 1) acc = fmaf(xr[-1 * 4096], w.z, acc);
  acc = fmaf(xr[0], w.w, acc);
  xc[idx] = silu_(acc);
}

// ---------------------------------------------------------------------------
// Selective scan, thread per (b,d). Fused epilogue: (y + u*D)*silu(z).
// delta lives in the x-columns of xz (stride 4096); z in the z-columns.
// Writes result in-place over the u buffer (read-then-write).
// ---------------------------------------------------------------------------
__global__ __launch_bounds__(256) void scan_kernel(
    const float* __restrict__ xz, float* __restrict__ u_y,
    const float* __restrict__ xdbl, const float* __restrict__ Aws,
    const float* __restrict__ Dp)
{
  const int b = blockIdx.x >> 3;
  const int d = ((blockIdx.x & 7) << 8) | threadIdx.x;
  float Ar[16];
#pragma unroll
  for (int n = 0; n < 16; ++n) Ar[n] = Aws[(d << 4) + n];
  const float Dd = Dp[d];
  float s[16];
#pragma unroll
  for (int n = 0; n < 16; ++n) s[n] = 0.f;

  const float* dp = xz + ((size_t)b << 23) + d;        // delta (stride 4096)
  const float* zp = xz + ((size_t)b << 23) + DI + d;   // z     (stride 4096)
  float* up = u_y + ((size_t)b << 22) + d;             // u/y   (stride 2048)
  const float* bc = xdbl + (size_t)b * (LSEQ * 96) + 64;

  for (int l = 0; l < LSEQ; ++l) {
    const float dt = dp[(size_t)l << 12];
    const float u = up[(size_t)l << 11];
    const float z = zp[(size_t)l << 12];
    const float du = dt * u;
    const float* bcl = bc + l * 96;
    float y = 0.f;
#pragma unroll
    for (int n = 0; n < 16; ++n) {
      const float Bn = bcl[n];
      const float Cn = bcl[16 + n];
      s[n] = fmaf(s[n], __expf(dt * Ar[n]), du * Bn);
      y = fmaf(s[n], Cn, y);
    }
    const float yv = fmaf(u, Dd, y);
    up[(size_t)l << 11] = yv * silu_(z);
  }
}

// ---------------------------------------------------------------------------
extern "C" void kernel_launch(void* const* d_in, const int* in_sizes, int n_in,
                              void* d_out, int out_size, void* d_ws, size_t ws_size,
                              hipStream_t stream)
{
  const float* hs         = (const float*)d_in[0];
  const float* in_proj_w  = (const float*)d_in[4];
  const float* conv_w     = (const float*)d_in[5];
  const float* conv_b     = (const float*)d_in[6];
  const float* x_proj_w   = (const float*)d_in[7];
  const float* dt_proj_w  = (const float*)d_in[8];
  const float* dt_proj_b  = (const float*)d_in[9];
  const float* A_log      = (const float*)d_in[10];
  const float* Dp         = (const float*)d_in[11];
  const float* out_proj_w = (const float*)d_in[12];
  float* out = (float*)d_out;
  float* ws = (float*)d_ws;

  float* xz    = ws + OFF_XZ;
  float* xc    = ws + OFF_XC;
  float* xdbl  = ws + OFF_XDBL;
  float* feats = ws + OFF_FEAT;
  float* norms = ws + OFF_NORM;
  float* Aws   = ws + OFF_AWS;

  const dim3 blk(256);

  // 1. xz = hs @ in_proj_w^T   (M=8192, N=4096, K=1024), layout (b,l,e)
  gemm_nt<0><<<dim3(64, 128), blk, 0, stream>>>(hs, DM, in_proj_w, DM, xz, E2, E2, DM, nullptr);
  // 2. channel-alignment features
  feat_kernel<<<4096, blk, 0, stream>>>(xz, feats);
  // 3. depthwise conv + silu
  conv_kernel<<<65536, blk, 0, stream>>>(xz, conv_w, conv_b, xc);
  // 4. per-frame feature norms
  norms_kernel<<<32, blk, 0, stream>>>(feats, norms);
  // 5. loss + alpha + A
  alpha_kernel<<<1, blk, 0, stream>>>(feats, norms, A_log, Aws, out + 8388608);
  // 6. x_dbl = xc @ x_proj_w^T   (M=8192, N=96, K=2048)
  gemm_nt<0><<<dim3(2, 128), blk, 0, stream>>>(xc, DI, x_proj_w, DI, xdbl, 96, 96, DI, nullptr);
  // 7. delta = softplus(x_dbl[:, :64] @ dt_proj_w^T + b) -> x-cols of xz
  //    (M=8192, N=2048, K=64, ldc=4096)
  gemm_nt<1><<<dim3(32, 128), blk, 0, stream>>>(xdbl, 96, dt_proj_w, 64, xz, E2, DI, 64, dt_proj_b);
  // 8. selective scan, fused epilogue, y overwrites xc
  scan_kernel<<<32, blk, 0, stream>>>(xz, xc, xdbl, Aws, Dp);
  // 9. out = y @ out_proj_w^T   (M=8192, N=1024, K=2048)
  gemm_nt<0><<<dim3(16, 128), blk, 0, stream>>>(xc, DI, out_proj_w, DI, out, DM, DM, DI, nullptr);
}

// Round 3
// 2053.926 us; speedup vs baseline: 1.4622x; 1.4622x over previous
//
#include <hip/hip_runtime.h>
#include <math.h>

// Problem constants (fixed instance)
#define LSEQ 2048
#define DM   1024
#define DI   2048
#define E2   4096
#define NC   32     // scan chunks per sequence
#define CL   64     // scan chunk length (NC*CL == LSEQ)

// workspace offsets (floats) — total 55,672,864 floats ~= 212.4 MiB
#define OFF_XZ    ((size_t)0)
#define OFF_XC    ((size_t)33554432)
#define OFF_XDBL  ((size_t)50331648)
#define OFF_FEAT  ((size_t)51118080)
#define OFF_NORM  ((size_t)51183616)
#define OFF_AWS   ((size_t)51183648)
#define OFF_CS    ((size_t)51216416)   // chunk states: 4*32*2048*16
#define OFF_SDT   ((size_t)55410720)   // per-chunk sum(dt): 4*32*2048
// delta is stored in-place over the x-columns of xz (stride 4096), which are
// dead after feat_kernel + conv_kernel have run.

__device__ __forceinline__ float silu_(float x) { return x / (1.f + __expf(-x)); }
__device__ __forceinline__ float softplus_(float x) {
  return fmaxf(x, 0.f) + log1pf(__expf(-fabsf(x)));
}

// ---------------------------------------------------------------------------
// Generic NT GEMM: C[M,N] = A[M,K] * B[N,K]^T, all row-major, K-contiguous.
// 64x64 tile, BK=16, 256 threads, 4x4 microtile. M assumed multiple of 64,
// K multiple of 16. N guarded. EPI: 0 = none, 1 = softplus(acc + bias[n]).
// ---------------------------------------------------------------------------
template <int EPI>
__global__ __launch_bounds__(256) void gemm_nt(
    const float* __restrict__ A, int lda,
    const float* __restrict__ B, int ldb,
    float* __restrict__ C, int ldc,
    int N, int K, const float* __restrict__ bias)
{
  __shared__ float As[16][68];
  __shared__ float Bs[16][68];
  const int tid = threadIdx.x;
  const int bm = blockIdx.y << 6;
  const int bn = blockIdx.x << 6;
  const int lr = tid >> 2;          // 0..63 : row within tile for loading
  const int lk = (tid & 3) << 2;    // 0,4,8,12 : k offset for loading
  const int tx = tid & 15, ty = tid >> 4;

  float acc[4][4];
#pragma unroll
  for (int i = 0; i < 4; ++i)
#pragma unroll
    for (int j = 0; j < 4; ++j) acc[i][j] = 0.f;

  const float* Ap = A + (size_t)(bm + lr) * lda + lk;
  const float* Bp = B + (size_t)(bn + lr) * ldb + lk;
  const bool bv = (bn + lr) < N;

  for (int k0 = 0; k0 < K; k0 += 16) {
    float4 a4 = *(const float4*)(Ap + k0);
    float4 b4 = bv ? *(const float4*)(Bp + k0) : make_float4(0.f, 0.f, 0.f, 0.f);
    __syncthreads();
    As[lk + 0][lr] = a4.x; As[lk + 1][lr] = a4.y;
    As[lk + 2][lr] = a4.z; As[lk + 3][lr] = a4.w;
    Bs[lk + 0][lr] = b4.x; Bs[lk + 1][lr] = b4.y;
    Bs[lk + 2][lr] = b4.z; Bs[lk + 3][lr] = b4.w;
    __syncthreads();
#pragma unroll
    for (int k = 0; k < 16; ++k) {
      const float4 av = *(const float4*)(&As[k][ty << 2]);
      const float4 bw = *(const float4*)(&Bs[k][tx << 2]);
      float a4r[4] = {av.x, av.y, av.z, av.w};
      float b4r[4] = {bw.x, bw.y, bw.z, bw.w};
#pragma unroll
      for (int i = 0; i < 4; ++i)
#pragma unroll
        for (int j = 0; j < 4; ++j)
          acc[i][j] = fmaf(a4r[i], b4r[j], acc[i][j]);
    }
  }

  const int m = bm + (ty << 2);
  const int n = bn + (tx << 2);
#pragma unroll
  for (int i = 0; i < 4; ++i) {
    float v[4] = {acc[i][0], acc[i][1], acc[i][2], acc[i][3]};
    if (EPI == 1) {
#pragma unroll
      for (int j = 0; j < 4; ++j)
        if (n + j < N) v[j] = softplus_(v[j] + bias[n + j]);
    }
    if (n + 3 < N) {
      *(float4*)(C + (size_t)(m + i) * ldc + n) = make_float4(v[0], v[1], v[2], v[3]);
    } else {
#pragma unroll
      for (int j = 0; j < 4; ++j)
        if (n + j < N) C[(size_t)(m + i) * ldc + n + j] = v[j];
    }
  }
}

// ---------------------------------------------------------------------------
// Channel alignment features (rfft2 16x16 magnitude band ratio).
// ---------------------------------------------------------------------------
__global__ __launch_bounds__(256) void feat_kernel(
    const float* __restrict__ xz, float* __restrict__ features)
{
  __shared__ float xin[256][17];       // [hw][ci]
  __shared__ float Rf[16 * 315];       // [ci]*315 + [kw]*35 + 2h+{0,1}
  __shared__ float tc[16], ts[16];
  __shared__ float part[16][9][2];

  const int tid = threadIdx.x;
  const int frame = blockIdx.x >> 7;   // b*8 + t
  const int cg = blockIdx.x & 127;
  const int b = frame >> 3, t = frame & 7;
  const int c0 = cg << 4;

  if (tid < 16) {
    float ang = 0.39269908169872414f * (float)tid;  // 2*pi*tid/16
    tc[tid] = cosf(ang);
    ts[tid] = sinf(ang);
  }
  const float* xb = xz + ((size_t)(b * LSEQ + t * 256) << 12) + c0;
  for (int i = tid; i < 256 * 16; i += 256) {
    int hw = i >> 4, ci = i & 15;
    xin[hw][ci] = xb[((size_t)hw << 12) + ci];
  }
  __syncthreads();

  {
    const int ci = tid & 15, h = tid >> 4;
    float re[9], im[9];
#pragma unroll
    for (int kw = 0; kw < 9; ++kw) { re[kw] = 0.f; im[kw] = 0.f; }
#pragma unroll
    for (int w = 0; w < 16; ++w) {
      float x = xin[(h << 4) + w][ci];
#pragma unroll
      for (int kw = 0; kw < 9; ++kw) {
        int ph = (kw * w) & 15;
        re[kw] = fmaf(x, tc[ph], re[kw]);
        im[kw] = fmaf(-x, ts[ph], im[kw]);
      }
    }
#pragma unroll
    for (int kw = 0; kw < 9; ++kw) {
      Rf[ci * 315 + kw * 35 + 2 * h]     = re[kw];
      Rf[ci * 315 + kw * 35 + 2 * h + 1] = im[kw];
    }
  }
  __syncthreads();

  if (tid < 144) {
    const int ci = tid & 15, kw = tid >> 4;  // kw in 0..8
    float ut = 0.f, tt = 0.f;
    for (int kh = 0; kh < 16; ++kh) {
      float fre = 0.f, fim = 0.f;
#pragma unroll
      for (int h = 0; h < 16; ++h) {
        int ph = (kh * h) & 15;
        float c = tc[ph], s = ts[ph];
        float rr = Rf[ci * 315 + kw * 35 + 2 * h];
        float ri = Rf[ci * 315 + kw * 35 + 2 * h + 1];
        fre += rr * c + ri * s;
        fim += ri * c - rr * s;
      }
      float mag = sqrtf(fre * fre + fim * fim + 1e-8f);
      int sh = (kh + 8) & 15;
      int sw = kw + 4; if (sw >= 9) sw -= 9;
      float dh = (float)(sh - 8) / 16.0f;
      float dw = (float)(sw - 4) / 9.0f;
      tt += mag;
      if (dh * dh + dw * dw >= 0.25f) ut += mag;
    }
    part[ci][kw][0] = ut;
    part[ci][kw][1] = tt;
  }
  __syncthreads();

  if (tid < 16) {
    float ut = 0.f, tt = 0.f;
    for (int kw = 0; kw < 9; ++kw) { ut += part[tid][kw][0]; tt += part[tid][kw][1]; }
    features[frame * DI + c0 + tid] = ut / (tt + 1e-8f);
  }
}

// ---------------------------------------------------------------------------
__global__ __launch_bounds__(256) void norms_kernel(
    const float* __restrict__ feats, float* __restrict__ norms)
{
  __shared__ float red[256];
  const int i = blockIdx.x, tid = threadIdx.x;
  float ss = 0.f;
  for (int d = tid; d < DI; d += 256) {
    float v = feats[i * DI + d];
    ss = fmaf(v, v, ss);
  }
  red[tid] = ss; __syncthreads();
  for (int s = 128; s > 0; s >>= 1) {
    if (tid < s) red[tid] += red[tid + s];
    __syncthreads();
  }
  if (tid == 0) norms[i] = sqrtf(red[0]);
}

// ---------------------------------------------------------------------------
// loss + softmax(mean feat) + attention + A_max/A_min + A output. One block.
// ---------------------------------------------------------------------------
__global__ __launch_bounds__(256) void alpha_kernel(
    const float* __restrict__ feats, const float* __restrict__ norms,
    const float* __restrict__ A_log, float* __restrict__ Aws,
    float* __restrict__ loss_out)
{
  __shared__ float red[256];
  __shared__ float invn[32];
  __shared__ float AM[256][17];
  __shared__ float sAmax[16], sAmin[16];
  const int tid = threadIdx.x;
  if (tid < 32) invn[tid] = 1.f / fmaxf(norms[tid], 1e-12f);
  __syncthreads();

  float md[8]; float gsq = 0.f;
#pragma unroll
  for (int j = 0; j < 8; ++j) {
    const int d = tid + (j << 8);
    float gd = 0.f, sm = 0.f;
    for (int i = 0; i < 32; ++i) {
      float v = feats[(i << 11) + d];
      gd = fmaf(v, invn[i], gd);
      sm += v;
    }
    md[j] = sm * (1.f / 32.f);
    gsq = fmaf(gd, gd, gsq);
  }
  red[tid] = gsq; __syncthreads();
  for (int s = 128; s > 0; s >>= 1) { if (tid < s) red[tid] += red[tid + s]; __syncthreads(); }
  if (tid == 0) loss_out[0] = 1.f - red[0] * (1.f / 1024.f);
  __syncthreads();

  float lm = md[0];
#pragma unroll
  for (int j = 1; j < 8; ++j) lm = fmaxf(lm, md[j]);
  red[tid] = lm; __syncthreads();
  for (int s = 128; s > 0; s >>= 1) { if (tid < s) red[tid] = fmaxf(red[tid], red[tid + s]); __syncthreads(); }
  const float mmax = red[0]; __syncthreads();

  float p[8]; float ps = 0.f;
#pragma unroll
  for (int j = 0; j < 8; ++j) { p[j] = __expf(md[j] - mmax); ps += p[j]; }
  red[tid] = ps; __syncthreads();
  for (int s = 128; s > 0; s >>= 1) { if (tid < s) red[tid] += red[tid + s]; __syncthreads(); }
  const float psum = red[0]; __syncthreads();

  float amaxl[16], aminl[16], rn[8];
#pragma unroll
  for (int n = 0; n < 16; ++n) { amaxl[n] = -1e30f; aminl[n] = 1e30f; }
#pragma unroll
  for (int j = 0; j < 8; ++j) {
    const int d = tid + (j << 8);
    float ss = 0.f;
#pragma unroll
    for (int n = 0; n < 16; ++n) {
      float a = A_log[(d << 4) + n];
      float e = __expf(a);
      ss = fmaf(e, e, ss);
      amaxl[n] = fmaxf(amaxl[n], a);
      aminl[n] = fminf(aminl[n], a);
    }
    rn[j] = sqrtf(ss);
  }
  float rm = rn[0];
#pragma unroll
  for (int j = 1; j < 8; ++j) rm = fmaxf(rm, rn[j]);
  red[tid] = rm; __syncthreads();
  for (int s = 128; s > 0; s >>= 1) { if (tid < s) red[tid] = fmaxf(red[tid], red[tid + s]); __syncthreads(); }
  const float rnmax = red[0]; __syncthreads();

#pragma unroll
  for (int n = 0; n < 16; ++n) AM[tid][n] = amaxl[n];
  __syncthreads();
  if (tid < 16) { float m = -1e30f; for (int i = 0; i < 256; ++i) m = fmaxf(m, AM[i][tid]); sAmax[tid] = m; }
  __syncthreads();
#pragma unroll
  for (int n = 0; n < 16; ++n) AM[tid][n] = aminl[n];
  __syncthreads();
  if (tid < 16) { float m = 1e30f; for (int i = 0; i < 256; ++i) m = fminf(m, AM[i][tid]); sAmin[tid] = m; }
  __syncthreads();

  const float irn = 1.f / (rnmax + 1e-8f);
#pragma unroll
  for (int j = 0; j < 8; ++j) {
    const int d = tid + (j << 8);
    const float att = rn[j] * irn;
    const float f = p[j] / psum;
    const float alpha = fminf(fmaxf(f * (1.f - att), 0.f), 1.f);
#pragma unroll
    for (int n = 0; n < 16; ++n) {
      float a = A_log[(d << 4) + n];
      float fl = sAmax[n] + sAmin[n] - a;
      float an = (1.f - alpha) * a + alpha * fl;
      Aws[(d << 4) + n] = -__expf(an);
    }
  }
}

// ---------------------------------------------------------------------------
// Depthwise causal conv (k=4) + bias + SiLU.  xz (b,l,e4096) -> xc (b,l,e2048)
// ---------------------------------------------------------------------------
__global__ __launch_bounds__(256) void conv_kernel(
    const float* __restrict__ xz, const float* __restrict__ cw,
    const float* __restrict__ cb, float* __restrict__ xc)
{
  const size_t idx = ((size_t)blockIdx.x << 8) + threadIdx.x;  // < 16777216
  const int e = (int)(idx & 2047);
  const int l = (int)((idx >> 11) & 2047);
  const int b = (int)(idx >> 22);
  const float* xr = xz + ((size_t)((b << 11) | l) << 12) + e;
  const float4 w = ((const float4*)cw)[e];
  float acc = cb[e];
  if (l >= 3) acc = fmaf(xr[-3 * 4096], w.x, acc);
  if (l >= 2) acc = fmaf(xr[-2 * 4096], w.y, acc);
  if (l >= 1) acc = fmaf(xr[-1 * 4096], w.z, acc);
  acc = fmaf(xr[0], w.w, acc);
  xc[idx] = silu_(acc);
}

// ---------------------------------------------------------------------------
// Chunked selective scan.
// s_{l} = s_{l-1} * exp(dt_l * A) + dt_l*u_l*B_l  — linear in s, diagonal
// transition; chunk transition operator = exp(A * sum(dt over chunk)).
// pass1: local scan (s0=0) per chunk -> store final local state + sum(dt).
// mid:   sequential combine over chunks -> overwrite buffer with s_init.
// pass3: re-run local scan from s_init, compute y + fused epilogue.
// grid pass1/pass3: b(4) x chunk(32) x dgroup(8) = 1024 blocks.
// ---------------------------------------------------------------------------
__global__ __launch_bounds__(256) void scan_pass1(
    const float* __restrict__ xz, const float* __restrict__ u_,
    const float* __restrict__ xdbl, const float* __restrict__ Aws,
    float* __restrict__ cs, float* __restrict__ sdt)
{
  __shared__ float blds[CL * 16];      // B rows for this chunk
  const int tid = threadIdx.x;
  const int dg = blockIdx.x & 7;
  const int chunk = (blockIdx.x >> 3) & 31;
  const int b = blockIdx.x >> 8;
  const int d = (dg << 8) | tid;
  const int l0 = chunk * CL;

  for (int i = tid; i < CL * 16; i += 256) {
    int l = i >> 4, j = i & 15;
    blds[i] = xdbl[(size_t)(b * LSEQ + l0 + l) * 96 + 64 + j];
  }
  __syncthreads();

  float Ar[16];
#pragma unroll
  for (int n = 0; n < 16; ++n) Ar[n] = Aws[(d << 4) + n];
  float s[16];
#pragma unroll
  for (int n = 0; n < 16; ++n) s[n] = 0.f;
  float sumdt = 0.f;

  const float* dp = xz + ((size_t)b << 23) + ((size_t)l0 << 12) + d;
  const float* up = u_ + ((size_t)b << 22) + ((size_t)l0 << 11) + d;

  for (int l = 0; l < CL; ++l) {
    const float dt = dp[(size_t)l << 12];
    const float u = up[(size_t)l << 11];
    sumdt += dt;
    const float du = dt * u;
    const float* bl = &blds[l << 4];
#pragma unroll
    for (int n = 0; n < 16; ++n)
      s[n] = fmaf(s[n], __expf(dt * Ar[n]), du * bl[n]);
  }

  float* csp = cs + ((((size_t)b * NC + chunk) * 2048 + d) << 4);
#pragma unroll
  for (int n = 0; n < 4; ++n)
    *(float4*)(csp + (n << 2)) = make_float4(s[4*n], s[4*n+1], s[4*n+2], s[4*n+3]);
  sdt[((size_t)b * NC + chunk) * 2048 + d] = sumdt;
}

__global__ __launch_bounds__(256) void scan_mid(
    float* __restrict__ cs, const float* __restrict__ sdt,
    const float* __restrict__ Aws)
{
  const int b = blockIdx.x >> 3;
  const int d = ((blockIdx.x & 7) << 8) | threadIdx.x;
  float Ar[16];
#pragma unroll
  for (int n = 0; n < 16; ++n) Ar[n] = Aws[(d << 4) + n];
  float si[16];
#pragma unroll
  for (int n = 0; n < 16; ++n) si[n] = 0.f;

  for (int c = 0; c < NC; ++c) {
    const size_t base = ((size_t)b * NC + c) * 2048 + d;
    float* csp = cs + (base << 4);
    float sl[16];
#pragma unroll
    for (int n = 0; n < 4; ++n) {
      float4 v = *(const float4*)(csp + (n << 2));
      sl[4*n] = v.x; sl[4*n+1] = v.y; sl[4*n+2] = v.z; sl[4*n+3] = v.w;
    }
    const float sm = sdt[base];
    // overwrite with s_init for this chunk
#pragma unroll
    for (int n = 0; n < 4; ++n)
      *(float4*)(csp + (n << 2)) = make_float4(si[4*n], si[4*n+1], si[4*n+2], si[4*n+3]);
    // advance: s_init_next = s_loc + exp(A*sumdt)*s_init
#pragma unroll
    for (int n = 0; n < 16; ++n)
      si[n] = fmaf(si[n], __expf(sm * Ar[n]), sl[n]);
  }
}

__global__ __launch_bounds__(256) void scan_pass3(
    const float* __restrict__ xz, float* __restrict__ u_y,
    const float* __restrict__ xdbl, const float* __restrict__ Aws,
    const float* __restrict__ Dp, const float* __restrict__ cs)
{
  __shared__ float bclds[CL * 32];     // B and C rows for this chunk
  const int tid = threadIdx.x;
  const int dg = blockIdx.x & 7;
  const int chunk = (blockIdx.x >> 3) & 31;
  const int b = blockIdx.x >> 8;
  const int d = (dg << 8) | tid;
  const int l0 = chunk * CL;

  for (int i = tid; i < CL * 32; i += 256) {
    int l = i >> 5, j = i & 31;
    bclds[i] = xdbl[(size_t)(b * LSEQ + l0 + l) * 96 + 64 + j];
  }
  __syncthreads();

  float Ar[16];
#pragma unroll
  for (int n = 0; n < 16; ++n) Ar[n] = Aws[(d << 4) + n];
  const float Dd = Dp[d];

  const float* csp = cs + ((((size_t)b * NC + chunk) * 2048 + d) << 4);
  float s[16];
#pragma unroll
  for (int n = 0; n < 4; ++n) {
    float4 v = *(const float4*)(csp + (n << 2));
    s[4*n] = v.x; s[4*n+1] = v.y; s[4*n+2] = v.z; s[4*n+3] = v.w;
  }

  const float* dp = xz + ((size_t)b << 23) + ((size_t)l0 << 12) + d;
  const float* zp = dp + DI;
  float* up = u_y + ((size_t)b << 22) + ((size_t)l0 << 11) + d;

  for (int l = 0; l < CL; ++l) {
    const float dt = dp[(size_t)l << 12];
    const float u = up[(size_t)l << 11];
    const float z = zp[(size_t)l << 12];
    const float du = dt * u;
    const float* bcl = &bclds[l << 5];
    float y = 0.f;
#pragma unroll
    for (int n = 0; n < 16; ++n) {
      s[n] = fmaf(s[n], __expf(dt * Ar[n]), du * bcl[n]);
      y = fmaf(s[n], bcl[16 + n], y);
    }
    const float yv = fmaf(u, Dd, y);
    up[(size_t)l << 11] = yv * silu_(z);
  }
}

// ---------------------------------------------------------------------------
extern "C" void kernel_launch(void* const* d_in, const int* in_sizes, int n_in,
                              void* d_out, int out_size, void* d_ws, size_t ws_size,
                              hipStream_t stream)
{
  const float* hs         = (const float*)d_in[0];
  const float* in_proj_w  = (const float*)d_in[4];
  const float* conv_w     = (const float*)d_in[5];
  const float* conv_b     = (const float*)d_in[6];
  const float* x_proj_w   = (const float*)d_in[7];
  const float* dt_proj_w  = (const float*)d_in[8];
  const float* dt_proj_b  = (const float*)d_in[9];
  const float* A_log      = (const float*)d_in[10];
  const float* Dp         = (const float*)d_in[11];
  const float* out_proj_w = (const float*)d_in[12];
  float* out = (float*)d_out;
  float* ws = (float*)d_ws;

  float* xz    = ws + OFF_XZ;
  float* xc    = ws + OFF_XC;
  float* xdbl  = ws + OFF_XDBL;
  float* feats = ws + OFF_FEAT;
  float* norms = ws + OFF_NORM;
  float* Aws   = ws + OFF_AWS;
  float* cs    = ws + OFF_CS;
  float* sdt   = ws + OFF_SDT;

  const dim3 blk(256);

  // 1. xz = hs @ in_proj_w^T   (M=8192, N=4096, K=1024), layout (b,l,e)
  gemm_nt<0><<<dim3(64, 128), blk, 0, stream>>>(hs, DM, in_proj_w, DM, xz, E2, E2, DM, nullptr);
  // 2. channel-alignment features
  feat_kernel<<<4096, blk, 0, stream>>>(xz, feats);
  // 3. depthwise conv + silu
  conv_kernel<<<65536, blk, 0, stream>>>(xz, conv_w, conv_b, xc);
  // 4. per-frame feature norms
  norms_kernel<<<32, blk, 0, stream>>>(feats, norms);
  // 5. loss + alpha + A
  alpha_kernel<<<1, blk, 0, stream>>>(feats, norms, A_log, Aws, out + 8388608);
  // 6. x_dbl = xc @ x_proj_w^T   (M=8192, N=96, K=2048)
  gemm_nt<0><<<dim3(2, 128), blk, 0, stream>>>(xc, DI, x_proj_w, DI, xdbl, 96, 96, DI, nullptr);
  // 7. delta = softplus(x_dbl[:, :64] @ dt_proj_w^T + b) -> x-cols of xz
  gemm_nt<1><<<dim3(32, 128), blk, 0, stream>>>(xdbl, 96, dt_proj_w, 64, xz, E2, DI, 64, dt_proj_b);
  // 8. chunked selective scan; y overwrites xc
  scan_pass1<<<1024, blk, 0, stream>>>(xz, xc, xdbl, Aws, cs, sdt);
  scan_mid<<<32, blk, 0, stream>>>(cs, sdt, Aws);
  scan_pass3<<<1024, blk, 0, stream>>>(xz, xc, xdbl, Aws, Dp, cs);
  // 9. out = y @ out_proj_w^T   (M=8192, N=1024, K=2048)
  gemm_nt<0><<<dim3(16, 128), blk, 0, stream>>>(xc, DI, out_proj_w, DI, out, DM, DM, DI, nullptr);
}

// Round 4
// 1062.185 us; speedup vs baseline: 2.8274x; 1.9337x over previous
//
#include <hip/hip_runtime.h>
#include <math.h>
#include <stdint.h>

// Problem constants (fixed instance)
#define LSEQ 2048
#define DM   1024
#define DI   2048
#define NC   32     // scan chunks per sequence
#define CL   64     // scan chunk length (NC*CL == LSEQ)

// ---------------------------------------------------------------------------
// Workspace layout (float units). Total 62,914,560 floats = 251.7 MB.
//  X  [0,          16777216)  : x half of in_proj output; later delta (in place)
//  Z  [16777216,   33554432)  : z half
//  U  [33554432,   50331648)  : conv output u -> y (in place) -> y split-bf16
//  S  [50331648,   58720256)  : A1' (hs split bf16[8192][2048]) until gemm1 done,
//                               then cs/sdt/xdbl/feats/norms/Aws overlay
//  B1 [58720256,   62914560)  : B1' (in_proj split) -> B2' (out_proj split)
// ---------------------------------------------------------------------------
#define OFF_X     ((size_t)0)
#define OFF_Z     ((size_t)16777216)
#define OFF_U     ((size_t)33554432)
#define OFF_S     ((size_t)50331648)
#define OFF_CS    (OFF_S)                      // 4,194,304 floats
#define OFF_SDT   (OFF_S + 4194304)            //   262,144
#define OFF_XDBL  (OFF_S + 4456448)            //   786,432
#define OFF_FEAT  (OFF_S + 5242880)            //    65,536
#define OFF_NORM  (OFF_S + 5308416)            //        32
#define OFF_AWS   (OFF_S + 5308448)            //    32,768
#define OFF_B1    ((size_t)58720256)

__device__ __forceinline__ float silu_(float x) { return x / (1.f + __expf(-x)); }
__device__ __forceinline__ float softplus_(float x) {
  return fmaxf(x, 0.f) + log1pf(__expf(-fabsf(x)));
}
__device__ __forceinline__ unsigned short f2bf(float x) {
  unsigned int u = __float_as_uint(x);
  u += 0x7fffu + ((u >> 16) & 1u);      // RNE (inputs finite)
  return (unsigned short)(u >> 16);
}
__device__ __forceinline__ float bf2f(unsigned short h) {
  return __uint_as_float(((unsigned int)h) << 16);
}

typedef __attribute__((ext_vector_type(8))) short bf16x8;
typedef __attribute__((ext_vector_type(4))) float f32x4;

__device__ __forceinline__ void gl2lds16(const void* g, void* l) {
  __builtin_amdgcn_global_load_lds(
      (const __attribute__((address_space(1))) unsigned int*)(uintptr_t)g,
      (__attribute__((address_space(3))) unsigned int*)(uintptr_t)l,
      16, 0, 0);
}

// ---------------------------------------------------------------------------
// Split fp32 -> [hi | lo] bf16 per row. K = 1<<kshift.
// ---------------------------------------------------------------------------
__global__ __launch_bounds__(256) void split_w(
    const float* __restrict__ in, unsigned short* __restrict__ out, int kshift)
{
  const size_t idx = ((size_t)blockIdx.x << 8) + threadIdx.x;
  const int K = 1 << kshift;
  const size_t row = idx >> kshift;
  const int k = (int)(idx & (K - 1));
  const float x = in[idx];
  const unsigned short h = f2bf(x);
  const unsigned short lo = f2bf(x - bf2f(h));
  unsigned short* o = out + (row << (kshift + 1));
  o[k] = h;
  o[K + k] = lo;
}

// ---------------------------------------------------------------------------
// In-place fp32 row [2048] -> bf16 [hi 2048 | lo 2048] (same 8 KB). One block
// per row; read-all, barrier, write-all.
// ---------------------------------------------------------------------------
__global__ __launch_bounds__(256) void split_inplace(float* __restrict__ buf)
{
  float* p = buf + ((size_t)blockIdx.x << 11);
  const int t = threadIdx.x;
  float4 v0 = ((const float4*)p)[t * 2];
  float4 v1 = ((const float4*)p)[t * 2 + 1];
  __syncthreads();
  float f[8] = {v0.x, v0.y, v0.z, v0.w, v1.x, v1.y, v1.z, v1.w};
  unsigned int hp[4], lp[4];
#pragma unroll
  for (int i = 0; i < 4; ++i) {
    unsigned short h0 = f2bf(f[2*i]),   l0 = f2bf(f[2*i]   - bf2f(h0));
    unsigned short h1 = f2bf(f[2*i+1]), l1 = f2bf(f[2*i+1] - bf2f(h1));
    hp[i] = (unsigned int)h0 | ((unsigned int)h1 << 16);
    lp[i] = (unsigned int)l0 | ((unsigned int)l1 << 16);
  }
  uint4* o = (uint4*)p;
  o[t]       = make_uint4(hp[0], hp[1], hp[2], hp[3]);
  o[256 + t] = make_uint4(lp[0], lp[1], lp[2], lp[3]);
}

// ---------------------------------------------------------------------------
// Split-bf16 MFMA GEMM: C[M,N] = A·B^T over logical K'=3K using segments
// (a_hi·b_hi + a_hi·b_lo + a_lo·b_hi). A[M][2K], B[N][2K] bf16 [hi|lo].
// 128x128 tile, 4 waves (2x2 of 64x64), BK=32, 16x16x32 MFMA,
// global_load_lds width-16 staging. WRITE_SPLIT: cols<2048 -> C0, else C1.
// ---------------------------------------------------------------------------
template <int WRITE_SPLIT>
__global__ __launch_bounds__(256) void gemm_mfma(
    const unsigned short* __restrict__ Ap, const unsigned short* __restrict__ Bp,
    float* __restrict__ C0, float* __restrict__ C1, int K, int ldc)
{
  __shared__ unsigned short As[128 * 32];
  __shared__ unsigned short Bs[128 * 32];
  const int tid = threadIdx.x;
  const int bn = blockIdx.x << 7;
  const int bm = blockIdx.y << 7;
  const int K2 = K * 2;

  const int wave = tid >> 6, lane = tid & 63;
  const int wm = (wave >> 1) << 6, wn = (wave & 1) << 6;
  const int lm = lane & 15, quad = lane >> 4;

  f32x4 acc[4][4] = {};

  // staging: chunk c covers row c>>2, k-offset (c&3)*8 (16 B). q=0: rows 0..63,
  // q=1: rows 64..127. LDS addr = c*16 (linear in lane — required by HW).
  const int r0 = tid >> 2, ko0 = (tid & 3) << 3;
  const unsigned short* Ag0 = Ap + (size_t)(bm + r0) * K2 + ko0;
  const unsigned short* Ag1 = Ap + (size_t)(bm + 64 + r0) * K2 + ko0;
  const unsigned short* Bg0 = Bp + (size_t)(bn + r0) * K2 + ko0;
  const unsigned short* Bg1 = Bp + (size_t)(bn + 64 + r0) * K2 + ko0;
  unsigned short* Al0 = &As[(size_t)tid * 8];
  unsigned short* Al1 = &As[(size_t)(256 + tid) * 8];
  unsigned short* Bl0 = &Bs[(size_t)tid * 8];
  unsigned short* Bl1 = &Bs[(size_t)(256 + tid) * 8];

  for (int sg = 0; sg < 3; ++sg) {
    const int ao = (sg == 2) ? K : 0;   // A segment offset (hi,hi,lo)
    const int bo = (sg == 1) ? K : 0;   // B segment offset (hi,lo,hi)
    for (int k0 = 0; k0 < K; k0 += 32) {
      __syncthreads();
      gl2lds16(Ag0 + ao + k0, Al0);
      gl2lds16(Ag1 + ao + k0, Al1);
      gl2lds16(Bg0 + bo + k0, Bl0);
      gl2lds16(Bg1 + bo + k0, Bl1);
      __syncthreads();
      bf16x8 af[4], bfr[4];
#pragma unroll
      for (int i = 0; i < 4; ++i)
        af[i] = *(const bf16x8*)&As[(wm + i * 16 + lm) * 32 + quad * 8];
#pragma unroll
      for (int j = 0; j < 4; ++j)
        bfr[j] = *(const bf16x8*)&Bs[(wn + j * 16 + lm) * 32 + quad * 8];
#pragma unroll
      for (int i = 0; i < 4; ++i)
#pragma unroll
        for (int j = 0; j < 4; ++j)
          acc[i][j] = __builtin_amdgcn_mfma_f32_16x16x32_bf16(af[i], bfr[j], acc[i][j], 0, 0, 0);
    }
  }

  // epilogue: C/D layout col=lane&15 (n, from B), row=quad*4+reg (m, from A)
  float* Cb = C0;
  int nb = bn;
  if (WRITE_SPLIT && bn >= 2048) { Cb = C1; nb = bn - 2048; }
#pragma unroll
  for (int i = 0; i < 4; ++i) {
    const int m = bm + wm + i * 16 + quad * 4;
#pragma unroll
    for (int j = 0; j < 4; ++j) {
      const int n = nb + wn + j * 16 + lm;
#pragma unroll
      for (int r = 0; r < 4; ++r)
        Cb[(size_t)(m + r) * ldc + n] = acc[i][j][r];
    }
  }
}

// ---------------------------------------------------------------------------
// fp32 NT GEMM (small shapes): C[M,N] = A[M,K]·B[N,K]^T. 64x64 tile, BK=16.
// EPI: 0 none, 1 softplus(acc + bias[n]).
// ---------------------------------------------------------------------------
template <int EPI>
__global__ __launch_bounds__(256) void gemm_nt(
    const float* __restrict__ A, int lda,
    const float* __restrict__ B, int ldb,
    float* __restrict__ C, int ldc,
    int N, int K, const float* __restrict__ bias)
{
  __shared__ float As[16][68];
  __shared__ float Bs[16][68];
  const int tid = threadIdx.x;
  const int bm = blockIdx.y << 6;
  const int bn = blockIdx.x << 6;
  const int lr = tid >> 2;
  const int lk = (tid & 3) << 2;
  const int tx = tid & 15, ty = tid >> 4;

  float acc[4][4];
#pragma unroll
  for (int i = 0; i < 4; ++i)
#pragma unroll
    for (int j = 0; j < 4; ++j) acc[i][j] = 0.f;

  const float* Apt = A + (size_t)(bm + lr) * lda + lk;
  const float* Bpt = B + (size_t)(bn + lr) * ldb + lk;
  const bool bv = (bn + lr) < N;

  for (int k0 = 0; k0 < K; k0 += 16) {
    float4 a4 = *(const float4*)(Apt + k0);
    float4 b4 = bv ? *(const float4*)(Bpt + k0) : make_float4(0.f, 0.f, 0.f, 0.f);
    __syncthreads();
    As[lk + 0][lr] = a4.x; As[lk + 1][lr] = a4.y;
    As[lk + 2][lr] = a4.z; As[lk + 3][lr] = a4.w;
    Bs[lk + 0][lr] = b4.x; Bs[lk + 1][lr] = b4.y;
    Bs[lk + 2][lr] = b4.z; Bs[lk + 3][lr] = b4.w;
    __syncthreads();
#pragma unroll
    for (int k = 0; k < 16; ++k) {
      const float4 av = *(const float4*)(&As[k][ty << 2]);
      const float4 bw = *(const float4*)(&Bs[k][tx << 2]);
      float a4r[4] = {av.x, av.y, av.z, av.w};
      float b4r[4] = {bw.x, bw.y, bw.z, bw.w};
#pragma unroll
      for (int i = 0; i < 4; ++i)
#pragma unroll
        for (int j = 0; j < 4; ++j)
          acc[i][j] = fmaf(a4r[i], b4r[j], acc[i][j]);
    }
  }

  const int m = bm + (ty << 2);
  const int n = bn + (tx << 2);
#pragma unroll
  for (int i = 0; i < 4; ++i) {
    float v[4] = {acc[i][0], acc[i][1], acc[i][2], acc[i][3]};
    if (EPI == 1) {
#pragma unroll
      for (int j = 0; j < 4; ++j)
        if (n + j < N) v[j] = softplus_(v[j] + bias[n + j]);
    }
    if (n + 3 < N) {
      *(float4*)(C + (size_t)(m + i) * ldc + n) = make_float4(v[0], v[1], v[2], v[3]);
    } else {
#pragma unroll
      for (int j = 0; j < 4; ++j)
        if (n + j < N) C[(size_t)(m + i) * ldc + n + j] = v[j];
    }
  }
}

// ---------------------------------------------------------------------------
// Channel alignment features (rfft2 16x16 magnitude band ratio). X stride 2048.
// ---------------------------------------------------------------------------
__global__ __launch_bounds__(256) void feat_kernel(
    const float* __restrict__ X, float* __restrict__ features)
{
  __shared__ float xin[256][17];
  __shared__ float Rf[16 * 315];
  __shared__ float tc[16], ts[16];
  __shared__ float part[16][9][2];

  const int tid = threadIdx.x;
  const int frame = blockIdx.x >> 7;
  const int cg = blockIdx.x & 127;
  const int b = frame >> 3, t = frame & 7;
  const int c0 = cg << 4;

  if (tid < 16) {
    float ang = 0.39269908169872414f * (float)tid;
    tc[tid] = cosf(ang);
    ts[tid] = sinf(ang);
  }
  const float* xb = X + ((size_t)(b * LSEQ + t * 256) << 11) + c0;
  for (int i = tid; i < 256 * 16; i += 256) {
    int hw = i >> 4, ci = i & 15;
    xin[hw][ci] = xb[((size_t)hw << 11) + ci];
  }
  __syncthreads();

  {
    const int ci = tid & 15, h = tid >> 4;
    float re[9], im[9];
#pragma unroll
    for (int kw = 0; kw < 9; ++kw) { re[kw] = 0.f; im[kw] = 0.f; }
#pragma unroll
    for (int w = 0; w < 16; ++w) {
      float x = xin[(h << 4) + w][ci];
#pragma unroll
      for (int kw = 0; kw < 9; ++kw) {
        int ph = (kw * w) & 15;
        re[kw] = fmaf(x, tc[ph], re[kw]);
        im[kw] = fmaf(-x, ts[ph], im[kw]);
      }
    }
#pragma unroll
    for (int kw = 0; kw < 9; ++kw) {
      Rf[ci * 315 + kw * 35 + 2 * h]     = re[kw];
      Rf[ci * 315 + kw * 35 + 2 * h + 1] = im[kw];
    }
  }
  __syncthreads();

  if (tid < 144) {
    const int ci = tid & 15, kw = tid >> 4;
    float ut = 0.f, tt = 0.f;
    for (int kh = 0; kh < 16; ++kh) {
      float fre = 0.f, fim = 0.f;
#pragma unroll
      for (int h = 0; h < 16; ++h) {
        int ph = (kh * h) & 15;
        float c = tc[ph], s = ts[ph];
        float rr = Rf[ci * 315 + kw * 35 + 2 * h];
        float ri = Rf[ci * 315 + kw * 35 + 2 * h + 1];
        fre += rr * c + ri * s;
        fim += ri * c - rr * s;
      }
      float mag = sqrtf(fre * fre + fim * fim + 1e-8f);
      int sh = (kh + 8) & 15;
      int sw = kw + 4; if (sw >= 9) sw -= 9;
      float dh = (float)(sh - 8) / 16.0f;
      float dw = (float)(sw - 4) / 9.0f;
      tt += mag;
      if (dh * dh + dw * dw >= 0.25f) ut += mag;
    }
    part[ci][kw][0] = ut;
    part[ci][kw][1] = tt;
  }
  __syncthreads();

  if (tid < 16) {
    float ut = 0.f, tt = 0.f;
    for (int kw = 0; kw < 9; ++kw) { ut += part[tid][kw][0]; tt += part[tid][kw][1]; }
    features[frame * DI + c0 + tid] = ut / (tt + 1e-8f);
  }
}

// ---------------------------------------------------------------------------
__global__ __launch_bounds__(256) void norms_kernel(
    const float* __restrict__ feats, float* __restrict__ norms)
{
  __shared__ float red[256];
  const int i = blockIdx.x, tid = threadIdx.x;
  float ss = 0.f;
  for (int d = tid; d < DI; d += 256) {
    float v = feats[i * DI + d];
    ss = fmaf(v, v, ss);
  }
  red[tid] = ss; __syncthreads();
  for (int s = 128; s > 0; s >>= 1) {
    if (tid < s) red[tid] += red[tid + s];
    __syncthreads();
  }
  if (tid == 0) norms[i] = sqrtf(red[0]);
}

// ---------------------------------------------------------------------------
// loss + softmax(mean feat) + attention + A_max/A_min + A output. One block.
// ---------------------------------------------------------------------------
__global__ __launch_bounds__(256) void alpha_kernel(
    const float* __restrict__ feats, const float* __restrict__ norms,
    const float* __restrict__ A_log, float* __restrict__ Aws,
    float* __restrict__ loss_out)
{
  __shared__ float red[256];
  __shared__ float invn[32];
  __shared__ float AM[256][17];
  __shared__ float sAmax[16], sAmin[16];
  const int tid = threadIdx.x;
  if (tid < 32) invn[tid] = 1.f / fmaxf(norms[tid], 1e-12f);
  __syncthreads();

  float md[8]; float gsq = 0.f;
#pragma unroll
  for (int j = 0; j < 8; ++j) {
    const int d = tid + (j << 8);
    float gd = 0.f, sm = 0.f;
    for (int i = 0; i < 32; ++i) {
      float v = feats[(i << 11) + d];
      gd = fmaf(v, invn[i], gd);
      sm += v;
    }
    md[j] = sm * (1.f / 32.f);
    gsq = fmaf(gd, gd, gsq);
  }
  red[tid] = gsq; __syncthreads();
  for (int s = 128; s > 0; s >>= 1) { if (tid < s) red[tid] += red[tid + s]; __syncthreads(); }
  if (tid == 0) loss_out[0] = 1.f - red[0] * (1.f / 1024.f);
  __syncthreads();

  float lm = md[0];
#pragma unroll
  for (int j = 1; j < 8; ++j) lm = fmaxf(lm, md[j]);
  red[tid] = lm; __syncthreads();
  for (int s = 128; s > 0; s >>= 1) { if (tid < s) red[tid] = fmaxf(red[tid], red[tid + s]); __syncthreads(); }
  const float mmax = red[0]; __syncthreads();

  float p[8]; float ps = 0.f;
#pragma unroll
  for (int j = 0; j < 8; ++j) { p[j] = __expf(md[j] - mmax); ps += p[j]; }
  red[tid] = ps; __syncthreads();
  for (int s = 128; s > 0; s >>= 1) { if (tid < s) red[tid] += red[tid + s]; __syncthreads(); }
  const float psum = red[0]; __syncthreads();

  float amaxl[16], aminl[16], rn[8];
#pragma unroll
  for (int n = 0; n < 16; ++n) { amaxl[n] = -1e30f; aminl[n] = 1e30f; }
#pragma unroll
  for (int j = 0; j < 8; ++j) {
    const int d = tid + (j << 8);
    float ss = 0.f;
#pragma unroll
    for (int n = 0; n < 16; ++n) {
      float a = A_log[(d << 4) + n];
      float e = __expf(a);
      ss = fmaf(e, e, ss);
      amaxl[n] = fmaxf(amaxl[n], a);
      aminl[n] = fminf(aminl[n], a);
    }
    rn[j] = sqrtf(ss);
  }
  float rm = rn[0];
#pragma unroll
  for (int j = 1; j < 8; ++j) rm = fmaxf(rm, rn[j]);
  red[tid] = rm; __syncthreads();
  for (int s = 128; s > 0; s >>= 1) { if (tid < s) red[tid] = fmaxf(red[tid], red[tid + s]); __syncthreads(); }
  const float rnmax = red[0]; __syncthreads();

#pragma unroll
  for (int n = 0; n < 16; ++n) AM[tid][n] = amaxl[n];
  __syncthreads();
  if (tid < 16) { float m = -1e30f; for (int i = 0; i < 256; ++i) m = fmaxf(m, AM[i][tid]); sAmax[tid] = m; }
  __syncthreads();
#pragma unroll
  for (int n = 0; n < 16; ++n) AM[tid][n] = aminl[n];
  __syncthreads();
  if (tid < 16) { float m = 1e30f; for (int i = 0; i < 256; ++i) m = fminf(m, AM[i][tid]); sAmin[tid] = m; }
  __syncthreads();

  const float irn = 1.f / (rnmax + 1e-8f);
#pragma unroll
  for (int j = 0; j < 8; ++j) {
    const int d = tid + (j << 8);
    const float att = rn[j] * irn;
    const float f = p[j] / psum;
    const float alpha = fminf(fmaxf(f * (1.f - att), 0.f), 1.f);
#pragma unroll
    for (int n = 0; n < 16; ++n) {
      float a = A_log[(d << 4) + n];
      float fl = sAmax[n] + sAmin[n] - a;
      float an = (1.f - alpha) * a + alpha * fl;
      Aws[(d << 4) + n] = -__expf(an);
    }
  }
}

// ---------------------------------------------------------------------------
// Depthwise causal conv (k=4) + bias + SiLU.  X (b,l,2048) -> U (b,l,2048)
// ---------------------------------------------------------------------------
__global__ __launch_bounds__(256) void conv_kernel(
    const float* __restrict__ X, const float* __restrict__ cw,
    const float* __restrict__ cb, float* __restrict__ U)
{
  const size_t idx = ((size_t)blockIdx.x << 8) + threadIdx.x;
  const int e = (int)(idx & 2047);
  const int l = (int)((idx >> 11) & 2047);
  const float* xr = X + (idx & ~(size_t)2047) + e;   // same flat index layout
  const float4 w = ((const float4*)cw)[e];
  float acc = cb[e];
  if (l >= 3) acc = fmaf(xr[-3 * 2048], w.x, acc);
  if (l >= 2) acc = fmaf(xr[-2 * 2048], w.y, acc);
  if (l >= 1) acc = fmaf(xr[-1 * 2048], w.z, acc);
  acc = fmaf(xr[0], w.w, acc);
  U[idx] = silu_(acc);
}

// ---------------------------------------------------------------------------
// Chunked selective scan (delta in X region stride 2048, z in Z stride 2048).
// ---------------------------------------------------------------------------
__global__ __launch_bounds__(256) void scan_pass1(
    const float* __restrict__ delta, const float* __restrict__ U,
    const float* __restrict__ xdbl, const float* __restrict__ Aws,
    float* __restrict__ cs, float* __restrict__ sdt)
{
  __shared__ float blds[CL * 16];
  const int tid = threadIdx.x;
  const int dg = blockIdx.x & 7;
  const int chunk = (blockIdx.x >> 3) & 31;
  const int b = blockIdx.x >> 8;
  const int d = (dg << 8) | tid;
  const int l0 = chunk * CL;

  for (int i = tid; i < CL * 16; i += 256) {
    int l = i >> 4, j = i & 15;
    blds[i] = xdbl[(size_t)(b * LSEQ + l0 + l) * 96 + 64 + j];
  }
  __syncthreads();

  float Ar[16];
#pragma unroll
  for (int n = 0; n < 16; ++n) Ar[n] = Aws[(d << 4) + n];
  float s[16];
#pragma unroll
  for (int n = 0; n < 16; ++n) s[n] = 0.f;
  float sumdt = 0.f;

  const float* dp = delta + ((size_t)b << 22) + ((size_t)l0 << 11) + d;
  const float* up = U + ((size_t)b << 22) + ((size_t)l0 << 11) + d;

  for (int l = 0; l < CL; ++l) {
    const float dt = dp[(size_t)l << 11];
    const float u = up[(size_t)l << 11];
    sumdt += dt;
    const float du = dt * u;
    const float* bl = &blds[l << 4];
#pragma unroll
    for (int n = 0; n < 16; ++n)
      s[n] = fmaf(s[n], __expf(dt * Ar[n]), du * bl[n]);
  }

  float* csp = cs + ((((size_t)b * NC + chunk) * 2048 + d) << 4);
#pragma unroll
  for (int n = 0; n < 4; ++n)
    *(float4*)(csp + (n << 2)) = make_float4(s[4*n], s[4*n+1], s[4*n+2], s[4*n+3]);
  sdt[((size_t)b * NC + chunk) * 2048 + d] = sumdt;
}

__global__ __launch_bounds__(256) void scan_mid(
    float* __restrict__ cs, const float* __restrict__ sdt,
    const float* __restrict__ Aws)
{
  const int b = blockIdx.x >> 3;
  const int d = ((blockIdx.x & 7) << 8) | threadIdx.x;
  float Ar[16];
#pragma unroll
  for (int n = 0; n < 16; ++n) Ar[n] = Aws[(d << 4) + n];
  float si[16];
#pragma unroll
  for (int n = 0; n < 16; ++n) si[n] = 0.f;

  for (int c = 0; c < NC; ++c) {
    const size_t base = ((size_t)b * NC + c) * 2048 + d;
    float* csp = cs + (base << 4);
    float sl[16];
#pragma unroll
    for (int n = 0; n < 4; ++n) {
      float4 v = *(const float4*)(csp + (n << 2));
      sl[4*n] = v.x; sl[4*n+1] = v.y; sl[4*n+2] = v.z; sl[4*n+3] = v.w;
    }
    const float sm = sdt[base];
#pragma unroll
    for (int n = 0; n < 4; ++n)
      *(float4*)(csp + (n << 2)) = make_float4(si[4*n], si[4*n+1], si[4*n+2], si[4*n+3]);
#pragma unroll
    for (int n = 0; n < 16; ++n)
      si[n] = fmaf(si[n], __expf(sm * Ar[n]), sl[n]);
  }
}

__global__ __launch_bounds__(256) void scan_pass3(
    const float* __restrict__ delta, const float* __restrict__ Z,
    float* __restrict__ U,
    const float* __restrict__ xdbl, const float* __restrict__ Aws,
    const float* __restrict__ Dp, const float* __restrict__ cs)
{
  __shared__ float bclds[CL * 32];
  const int tid = threadIdx.x;
  const int dg = blockIdx.x & 7;
  const int chunk = (blockIdx.x >> 3) & 31;
  const int b = blockIdx.x >> 8;
  const int d = (dg << 8) | tid;
  const int l0 = chunk * CL;

  for (int i = tid; i < CL * 32; i += 256) {
    int l = i >> 5, j = i & 31;
    bclds[i] = xdbl[(size_t)(b * LSEQ + l0 + l) * 96 + 64 + j];
  }
  __syncthreads();

  float Ar[16];
#pragma unroll
  for (int n = 0; n < 16; ++n) Ar[n] = Aws[(d << 4) + n];
  const float Dd = Dp[d];

  const float* csp = cs + ((((size_t)b * NC + chunk) * 2048 + d) << 4);
  float s[16];
#pragma unroll
  for (int n = 0; n < 4; ++n) {
    float4 v = *(const float4*)(csp + (n << 2));
    s[4*n] = v.x; s[4*n+1] = v.y; s[4*n+2] = v.z; s[4*n+3] = v.w;
  }

  const float* dp = delta + ((size_t)b << 22) + ((size_t)l0 << 11) + d;
  const float* zp = Z + ((size_t)b << 22) + ((size_t)l0 << 11) + d;
  float* up = U + ((size_t)b << 22) + ((size_t)l0 << 11) + d;

  for (int l = 0; l < CL; ++l) {
    const float dt = dp[(size_t)l << 11];
    const float u = up[(size_t)l << 11];
    const float z = zp[(size_t)l << 11];
    const float du = dt * u;
    const float* bcl = &bclds[l << 5];
    float y = 0.f;
#pragma unroll
    for (int n = 0; n < 16; ++n) {
      s[n] = fmaf(s[n], __expf(dt * Ar[n]), du * bcl[n]);
      y = fmaf(s[n], bcl[16 + n], y);
    }
    const float yv = fmaf(u, Dd, y);
    up[(size_t)l << 11] = yv * silu_(z);
  }
}

// ---------------------------------------------------------------------------
extern "C" void kernel_launch(void* const* d_in, const int* in_sizes, int n_in,
                              void* d_out, int out_size, void* d_ws, size_t ws_size,
                              hipStream_t stream)
{
  const float* hs         = (const float*)d_in[0];
  const float* in_proj_w  = (const float*)d_in[4];
  const float* conv_w     = (const float*)d_in[5];
  const float* conv_b     = (const float*)d_in[6];
  const float* x_proj_w   = (const float*)d_in[7];
  const float* dt_proj_w  = (const float*)d_in[8];
  const float* dt_proj_b  = (const float*)d_in[9];
  const float* A_log      = (const float*)d_in[10];
  const float* Dp         = (const float*)d_in[11];
  const float* out_proj_w = (const float*)d_in[12];
  float* out = (float*)d_out;
  float* ws = (float*)d_ws;

  float* X     = ws + OFF_X;
  float* Z     = ws + OFF_Z;
  float* U     = ws + OFF_U;
  float* cs    = ws + OFF_CS;
  float* sdt   = ws + OFF_SDT;
  float* xdbl  = ws + OFF_XDBL;
  float* feats = ws + OFF_FEAT;
  float* norms = ws + OFF_NORM;
  float* Aws   = ws + OFF_AWS;
  unsigned short* A1s = (unsigned short*)(ws + OFF_S);
  unsigned short* B1s = (unsigned short*)(ws + OFF_B1);
  unsigned short* B2s = (unsigned short*)(ws + OFF_B1);
  unsigned short* A2s = (unsigned short*)U;   // y split in place

  const dim3 blk(256);

  // 0. split hs and in_proj_w to [hi|lo] bf16
  split_w<<<32768, blk, 0, stream>>>(hs, A1s, 10);
  split_w<<<16384, blk, 0, stream>>>(in_proj_w, B1s, 10);
  // 1. xz = hs @ in_proj_w^T  (MFMA split, M=8192,N=4096,K=1024) -> X | Z
  gemm_mfma<1><<<dim3(32, 64), blk, 0, stream>>>(A1s, B1s, X, Z, 1024, 2048);
  // 2. channel-alignment features (reads X)
  feat_kernel<<<4096, blk, 0, stream>>>(X, feats);
  // 3. depthwise conv + silu (X -> U)
  conv_kernel<<<65536, blk, 0, stream>>>(X, conv_w, conv_b, U);
  // 3b. split out_proj_w (overlays dead B1s region)
  split_w<<<8192, blk, 0, stream>>>(out_proj_w, B2s, 11);
  // 4. per-frame feature norms
  norms_kernel<<<32, blk, 0, stream>>>(feats, norms);
  // 5. loss + alpha + A
  alpha_kernel<<<1, blk, 0, stream>>>(feats, norms, A_log, Aws, out + 8388608);
  // 6. x_dbl = U @ x_proj_w^T   (M=8192, N=96, K=2048)
  gemm_nt<0><<<dim3(2, 128), blk, 0, stream>>>(U, DI, x_proj_w, DI, xdbl, 96, 96, DI, nullptr);
  // 7. delta = softplus(x_dbl[:, :64] @ dt_proj_w^T + b) -> X region (dead x)
  gemm_nt<1><<<dim3(32, 128), blk, 0, stream>>>(xdbl, 96, dt_proj_w, 64, X, DI, DI, 64, dt_proj_b);
  // 8. chunked selective scan; y overwrites U (fp32)
  scan_pass1<<<1024, blk, 0, stream>>>(X, U, xdbl, Aws, cs, sdt);
  scan_mid<<<32, blk, 0, stream>>>(cs, sdt, Aws);
  scan_pass3<<<1024, blk, 0, stream>>>(X, Z, U, xdbl, Aws, Dp, cs);
  // 9. in-place split y -> bf16 [hi|lo]
  split_inplace<<<8192, blk, 0, stream>>>(U);
  // 10. out = y @ out_proj_w^T  (MFMA split, M=8192,N=1024,K=2048)
  gemm_mfma<0><<<dim3(8, 64), blk, 0, stream>>>(A2s, B2s, out, nullptr, 2048, 1024);
}

// Round 5
// 997.219 us; speedup vs baseline: 3.0116x; 1.0651x over previous
//
#include <hip/hip_runtime.h>
#include <math.h>
#include <stdint.h>

// Problem constants (fixed instance)
#define LSEQ 2048
#define DM   1024
#define DI   2048
#define NC   32     // scan chunks per sequence
#define CL   64     // scan chunk length (NC*CL == LSEQ)

// ---------------------------------------------------------------------------
// Workspace layout (float units). Total 62,914,560 floats = 251.7 MB.
//  X  [0,          16777216)  : x half of in_proj output; later delta (in place)
//  Z  [16777216,   33554432)  : z half
//  U  [33554432,   50331648)  : conv output u -> y (in place) -> y split-bf16
//  S  [50331648,   58720256)  : A1' (hs split bf16[8192][2048]) until gemm1 done,
//                               then cs/sdt/xdbl/feats/norms/Aws overlay
//  B1 [58720256,   62914560)  : B1' (in_proj split) -> B2' (out_proj split)
// ---------------------------------------------------------------------------
#define OFF_X     ((size_t)0)
#define OFF_Z     ((size_t)16777216)
#define OFF_U     ((size_t)33554432)
#define OFF_S     ((size_t)50331648)
#define OFF_CS    (OFF_S)                      // 4,194,304 floats
#define OFF_SDT   (OFF_S + 4194304)            //   262,144
#define OFF_XDBL  (OFF_S + 4456448)            //   786,432
#define OFF_FEAT  (OFF_S + 5242880)            //    65,536
#define OFF_NORM  (OFF_S + 5308416)            //        32
#define OFF_AWS   (OFF_S + 5308448)            //    32,768
#define OFF_B1    ((size_t)58720256)

__device__ __forceinline__ float silu_(float x) { return x / (1.f + __expf(-x)); }
__device__ __forceinline__ float softplus_(float x) {
  return fmaxf(x, 0.f) + log1pf(__expf(-fabsf(x)));
}
__device__ __forceinline__ unsigned short f2bf(float x) {
  unsigned int u = __float_as_uint(x);
  u += 0x7fffu + ((u >> 16) & 1u);      // RNE (inputs finite)
  return (unsigned short)(u >> 16);
}
__device__ __forceinline__ float bf2f(unsigned short h) {
  return __uint_as_float(((unsigned int)h) << 16);
}

typedef __attribute__((ext_vector_type(8))) short bf16x8;
typedef __attribute__((ext_vector_type(4))) float f32x4;

__device__ __forceinline__ void gl2lds16(const void* g, void* l) {
  __builtin_amdgcn_global_load_lds(
      (const __attribute__((address_space(1))) unsigned int*)(uintptr_t)g,
      (__attribute__((address_space(3))) unsigned int*)(uintptr_t)l,
      16, 0, 0);
}

// ---------------------------------------------------------------------------
// Split fp32 -> [hi | lo] bf16 per row. K = 1<<kshift.
// ---------------------------------------------------------------------------
__global__ __launch_bounds__(256) void split_w(
    const float* __restrict__ in, unsigned short* __restrict__ out, int kshift)
{
  const size_t idx = ((size_t)blockIdx.x << 8) + threadIdx.x;
  const int K = 1 << kshift;
  const size_t row = idx >> kshift;
  const int k = (int)(idx & (K - 1));
  const float x = in[idx];
  const unsigned short h = f2bf(x);
  const unsigned short lo = f2bf(x - bf2f(h));
  unsigned short* o = out + (row << (kshift + 1));
  o[k] = h;
  o[K + k] = lo;
}

// ---------------------------------------------------------------------------
// In-place fp32 row [2048] -> bf16 [hi 2048 | lo 2048] (same 8 KB). One block
// per row; read-all, barrier, write-all.
// ---------------------------------------------------------------------------
__global__ __launch_bounds__(256) void split_inplace(float* __restrict__ buf)
{
  float* p = buf + ((size_t)blockIdx.x << 11);
  const int t = threadIdx.x;
  float4 v0 = ((const float4*)p)[t * 2];
  float4 v1 = ((const float4*)p)[t * 2 + 1];
  __syncthreads();
  float f[8] = {v0.x, v0.y, v0.z, v0.w, v1.x, v1.y, v1.z, v1.w};
  unsigned int hp[4], lp[4];
#pragma unroll
  for (int i = 0; i < 4; ++i) {
    unsigned short h0 = f2bf(f[2*i]),   l0 = f2bf(f[2*i]   - bf2f(h0));
    unsigned short h1 = f2bf(f[2*i+1]), l1 = f2bf(f[2*i+1] - bf2f(h1));
    hp[i] = (unsigned int)h0 | ((unsigned int)h1 << 16);
    lp[i] = (unsigned int)l0 | ((unsigned int)l1 << 16);
  }
  uint4* o = (uint4*)p;
  o[t]       = make_uint4(hp[0], hp[1], hp[2], hp[3]);
  o[256 + t] = make_uint4(lp[0], lp[1], lp[2], lp[3]);
}

// ---------------------------------------------------------------------------
// Split-bf16 MFMA GEMM: C[M,N] = A·B^T with fp32-class accuracy via
// a_hi·b_hi + a_hi·b_lo + a_lo·b_hi. A[M][2K], B[N][2K] bf16 [hi|lo].
// 128x128 tile, 4 waves (2x2 of 64x64), BK=32, 16x16x32 MFMA.
// All four tiles (A_hi,A_lo,B_hi,B_lo) staged once per k0 via global_load_lds;
// 48 MFMAs per k0. XOR bank swizzle: LDS slot (r,q) holds k-chunk
// q^((r>>1)&3), making the b128 fragment reads 2-way (free) instead of 8-way.
// WRITE_SPLIT: cols<2048 -> C0, else C1.
// ---------------------------------------------------------------------------
template <int WRITE_SPLIT>
__global__ __launch_bounds__(256) void gemm_mfma(
    const unsigned short* __restrict__ Ap, const unsigned short* __restrict__ Bp,
    float* __restrict__ C0, float* __restrict__ C1, int K, int ldc)
{
  __shared__ unsigned short AsH[128 * 32];
  __shared__ unsigned short AsL[128 * 32];
  __shared__ unsigned short BsH[128 * 32];
  __shared__ unsigned short BsL[128 * 32];
  const int tid = threadIdx.x;
  const int bn = blockIdx.x << 7;
  const int bm = blockIdx.y << 7;
  const int K2 = K * 2;

  const int wave = tid >> 6, lane = tid & 63;
  const int wm = (wave >> 1) << 6, wn = (wave & 1) << 6;
  const int lm = lane & 15, quad = lane >> 4;
  const int sw = (lm >> 1) & 3;        // reader swizzle (row>>1)&3 == (lm>>1)&3

  f32x4 acc[4][4] = {};

  // staging: thread tid fills LDS slots tid (rows 0..63) and tid+256
  // (rows 64..127); slot s=(r,q) takes global k-chunk q^((r>>1)&3).
  const int r0 = tid >> 2;
  const int kq = ((tid & 3) ^ ((r0 >> 1) & 3)) << 3;   // element offset
  const unsigned short* AgH0 = Ap + (size_t)(bm + r0) * K2 + kq;
  const unsigned short* AgH1 = Ap + (size_t)(bm + 64 + r0) * K2 + kq;
  const unsigned short* BgH0 = Bp + (size_t)(bn + r0) * K2 + kq;
  const unsigned short* BgH1 = Bp + (size_t)(bn + 64 + r0) * K2 + kq;
  unsigned short* lA0 = &AsH[(size_t)tid * 8];
  unsigned short* lA1 = &AsH[(size_t)(256 + tid) * 8];
  unsigned short* lAl0 = &AsL[(size_t)tid * 8];
  unsigned short* lAl1 = &AsL[(size_t)(256 + tid) * 8];
  unsigned short* lB0 = &BsH[(size_t)tid * 8];
  unsigned short* lB1 = &BsH[(size_t)(256 + tid) * 8];
  unsigned short* lBl0 = &BsL[(size_t)tid * 8];
  unsigned short* lBl1 = &BsL[(size_t)(256 + tid) * 8];

  for (int k0 = 0; k0 < K; k0 += 32) {
    __syncthreads();
    gl2lds16(AgH0 + k0, lA0);
    gl2lds16(AgH1 + k0, lA1);
    gl2lds16(AgH0 + K + k0, lAl0);
    gl2lds16(AgH1 + K + k0, lAl1);
    gl2lds16(BgH0 + k0, lB0);
    gl2lds16(BgH1 + k0, lB1);
    gl2lds16(BgH0 + K + k0, lBl0);
    gl2lds16(BgH1 + K + k0, lBl1);
    __syncthreads();

    bf16x8 aH[4], aL[4], bH[4], bL[4];
#pragma unroll
    for (int i = 0; i < 4; ++i) {
      const int off = (wm + i * 16 + lm) * 32 + ((quad ^ sw) << 3);
      aH[i] = *(const bf16x8*)&AsH[off];
      aL[i] = *(const bf16x8*)&AsL[off];
    }
#pragma unroll
    for (int j = 0; j < 4; ++j) {
      const int off = (wn + j * 16 + lm) * 32 + ((quad ^ sw) << 3);
      bH[j] = *(const bf16x8*)&BsH[off];
      bL[j] = *(const bf16x8*)&BsL[off];
    }
#pragma unroll
    for (int i = 0; i < 4; ++i)
#pragma unroll
      for (int j = 0; j < 4; ++j) {
        acc[i][j] = __builtin_amdgcn_mfma_f32_16x16x32_bf16(aH[i], bH[j], acc[i][j], 0, 0, 0);
        acc[i][j] = __builtin_amdgcn_mfma_f32_16x16x32_bf16(aH[i], bL[j], acc[i][j], 0, 0, 0);
        acc[i][j] = __builtin_amdgcn_mfma_f32_16x16x32_bf16(aL[i], bH[j], acc[i][j], 0, 0, 0);
      }
  }

  // epilogue: C/D layout col=lane&15 (n, from B), row=quad*4+reg (m, from A)
  float* Cb = C0;
  int nb = bn;
  if (WRITE_SPLIT && bn >= 2048) { Cb = C1; nb = bn - 2048; }
#pragma unroll
  for (int i = 0; i < 4; ++i) {
    const int m = bm + wm + i * 16 + quad * 4;
#pragma unroll
    for (int j = 0; j < 4; ++j) {
      const int n = nb + wn + j * 16 + lm;
#pragma unroll
      for (int r = 0; r < 4; ++r)
        Cb[(size_t)(m + r) * ldc + n] = acc[i][j][r];
    }
  }
}

// ---------------------------------------------------------------------------
// fp32 NT GEMM (small shapes): C[M,N] = A[M,K]·B[N,K]^T. 64x64 tile, BK=16.
// EPI: 0 none, 1 softplus(acc + bias[n]).
// ---------------------------------------------------------------------------
template <int EPI>
__global__ __launch_bounds__(256) void gemm_nt(
    const float* __restrict__ A, int lda,
    const float* __restrict__ B, int ldb,
    float* __restrict__ C, int ldc,
    int N, int K, const float* __restrict__ bias)
{
  __shared__ float As[16][68];
  __shared__ float Bs[16][68];
  const int tid = threadIdx.x;
  const int bm = blockIdx.y << 6;
  const int bn = blockIdx.x << 6;
  const int lr = tid >> 2;
  const int lk = (tid & 3) << 2;
  const int tx = tid & 15, ty = tid >> 4;

  float acc[4][4];
#pragma unroll
  for (int i = 0; i < 4; ++i)
#pragma unroll
    for (int j = 0; j < 4; ++j) acc[i][j] = 0.f;

  const float* Apt = A + (size_t)(bm + lr) * lda + lk;
  const float* Bpt = B + (size_t)(bn + lr) * ldb + lk;
  const bool bv = (bn + lr) < N;

  for (int k0 = 0; k0 < K; k0 += 16) {
    float4 a4 = *(const float4*)(Apt + k0);
    float4 b4 = bv ? *(const float4*)(Bpt + k0) : make_float4(0.f, 0.f, 0.f, 0.f);
    __syncthreads();
    As[lk + 0][lr] = a4.x; As[lk + 1][lr] = a4.y;
    As[lk + 2][lr] = a4.z; As[lk + 3][lr] = a4.w;
    Bs[lk + 0][lr] = b4.x; Bs[lk + 1][lr] = b4.y;
    Bs[lk + 2][lr] = b4.z; Bs[lk + 3][lr] = b4.w;
    __syncthreads();
#pragma unroll
    for (int k = 0; k < 16; ++k) {
      const float4 av = *(const float4*)(&As[k][ty << 2]);
      const float4 bw = *(const float4*)(&Bs[k][tx << 2]);
      float a4r[4] = {av.x, av.y, av.z, av.w};
      float b4r[4] = {bw.x, bw.y, bw.z, bw.w};
#pragma unroll
      for (int i = 0; i < 4; ++i)
#pragma unroll
        for (int j = 0; j < 4; ++j)
          acc[i][j] = fmaf(a4r[i], b4r[j], acc[i][j]);
    }
  }

  const int m = bm + (ty << 2);
  const int n = bn + (tx << 2);
#pragma unroll
  for (int i = 0; i < 4; ++i) {
    float v[4] = {acc[i][0], acc[i][1], acc[i][2], acc[i][3]};
    if (EPI == 1) {
#pragma unroll
      for (int j = 0; j < 4; ++j)
        if (n + j < N) v[j] = softplus_(v[j] + bias[n + j]);
    }
    if (n + 3 < N) {
      *(float4*)(C + (size_t)(m + i) * ldc + n) = make_float4(v[0], v[1], v[2], v[3]);
    } else {
#pragma unroll
      for (int j = 0; j < 4; ++j)
        if (n + j < N) C[(size_t)(m + i) * ldc + n + j] = v[j];
    }
  }
}

// ---------------------------------------------------------------------------
// Channel alignment features (rfft2 16x16 magnitude band ratio). X stride 2048.
// ---------------------------------------------------------------------------
__global__ __launch_bounds__(256) void feat_kernel(
    const float* __restrict__ X, float* __restrict__ features)
{
  __shared__ float xin[256][17];
  __shared__ float Rf[16 * 315];
  __shared__ float tc[16], ts[16];
  __shared__ float part[16][9][2];

  const int tid = threadIdx.x;
  const int frame = blockIdx.x >> 7;
  const int cg = blockIdx.x & 127;
  const int b = frame >> 3, t = frame & 7;
  const int c0 = cg << 4;

  if (tid < 16) {
    float ang = 0.39269908169872414f * (float)tid;
    tc[tid] = cosf(ang);
    ts[tid] = sinf(ang);
  }
  const float* xb = X + ((size_t)(b * LSEQ + t * 256) << 11) + c0;
  for (int i = tid; i < 256 * 16; i += 256) {
    int hw = i >> 4, ci = i & 15;
    xin[hw][ci] = xb[((size_t)hw << 11) + ci];
  }
  __syncthreads();

  {
    const int ci = tid & 15, h = tid >> 4;
    float re[9], im[9];
#pragma unroll
    for (int kw = 0; kw < 9; ++kw) { re[kw] = 0.f; im[kw] = 0.f; }
#pragma unroll
    for (int w = 0; w < 16; ++w) {
      float x = xin[(h << 4) + w][ci];
#pragma unroll
      for (int kw = 0; kw < 9; ++kw) {
        int ph = (kw * w) & 15;
        re[kw] = fmaf(x, tc[ph], re[kw]);
        im[kw] = fmaf(-x, ts[ph], im[kw]);
      }
    }
#pragma unroll
    for (int kw = 0; kw < 9; ++kw) {
      Rf[ci * 315 + kw * 35 + 2 * h]     = re[kw];
      Rf[ci * 315 + kw * 35 + 2 * h + 1] = im[kw];
    }
  }
  __syncthreads();

  if (tid < 144) {
    const int ci = tid & 15, kw = tid >> 4;
    float ut = 0.f, tt = 0.f;
    for (int kh = 0; kh < 16; ++kh) {
      float fre = 0.f, fim = 0.f;
#pragma unroll
      for (int h = 0; h < 16; ++h) {
        int ph = (kh * h) & 15;
        float c = tc[ph], s = ts[ph];
        float rr = Rf[ci * 315 + kw * 35 + 2 * h];
        float ri = Rf[ci * 315 + kw * 35 + 2 * h + 1];
        fre += rr * c + ri * s;
        fim += ri * c - rr * s;
      }
      float mag = sqrtf(fre * fre + fim * fim + 1e-8f);
      int sh = (kh + 8) & 15;
      int sw2 = kw + 4; if (sw2 >= 9) sw2 -= 9;
      float dh = (float)(sh - 8) / 16.0f;
      float dw = (float)(sw2 - 4) / 9.0f;
      tt += mag;
      if (dh * dh + dw * dw >= 0.25f) ut += mag;
    }
    part[ci][kw][0] = ut;
    part[ci][kw][1] = tt;
  }
  __syncthreads();

  if (tid < 16) {
    float ut = 0.f, tt = 0.f;
    for (int kw = 0; kw < 9; ++kw) { ut += part[tid][kw][0]; tt += part[tid][kw][1]; }
    features[frame * DI + c0 + tid] = ut / (tt + 1e-8f);
  }
}

// ---------------------------------------------------------------------------
__global__ __launch_bounds__(256) void norms_kernel(
    const float* __restrict__ feats, float* __restrict__ norms)
{
  __shared__ float red[256];
  const int i = blockIdx.x, tid = threadIdx.x;
  float ss = 0.f;
  for (int d = tid; d < DI; d += 256) {
    float v = feats[i * DI + d];
    ss = fmaf(v, v, ss);
  }
  red[tid] = ss; __syncthreads();
  for (int s = 128; s > 0; s >>= 1) {
    if (tid < s) red[tid] += red[tid + s];
    __syncthreads();
  }
  if (tid == 0) norms[i] = sqrtf(red[0]);
}

// ---------------------------------------------------------------------------
// loss + softmax(mean feat) + attention + A_max/A_min + A output. One block.
// ---------------------------------------------------------------------------
__global__ __launch_bounds__(256) void alpha_kernel(
    const float* __restrict__ feats, const float* __restrict__ norms,
    const float* __restrict__ A_log, float* __restrict__ Aws,
    float* __restrict__ loss_out)
{
  __shared__ float red[256];
  __shared__ float invn[32];
  __shared__ float AM[256][17];
  __shared__ float sAmax[16], sAmin[16];
  const int tid = threadIdx.x;
  if (tid < 32) invn[tid] = 1.f / fmaxf(norms[tid], 1e-12f);
  __syncthreads();

  float md[8]; float gsq = 0.f;
#pragma unroll
  for (int j = 0; j < 8; ++j) {
    const int d = tid + (j << 8);
    float gd = 0.f, sm = 0.f;
    for (int i = 0; i < 32; ++i) {
      float v = feats[(i << 11) + d];
      gd = fmaf(v, invn[i], gd);
      sm += v;
    }
    md[j] = sm * (1.f / 32.f);
    gsq = fmaf(gd, gd, gsq);
  }
  red[tid] = gsq; __syncthreads();
  for (int s = 128; s > 0; s >>= 1) { if (tid < s) red[tid] += red[tid + s]; __syncthreads(); }
  if (tid == 0) loss_out[0] = 1.f - red[0] * (1.f / 1024.f);
  __syncthreads();

  float lm = md[0];
#pragma unroll
  for (int j = 1; j < 8; ++j) lm = fmaxf(lm, md[j]);
  red[tid] = lm; __syncthreads();
  for (int s = 128; s > 0; s >>= 1) { if (tid < s) red[tid] = fmaxf(red[tid], red[tid + s]); __syncthreads(); }
  const float mmax = red[0]; __syncthreads();

  float p[8]; float ps = 0.f;
#pragma unroll
  for (int j = 0; j < 8; ++j) { p[j] = __expf(md[j] - mmax); ps += p[j]; }
  red[tid] = ps; __syncthreads();
  for (int s = 128; s > 0; s >>= 1) { if (tid < s) red[tid] += red[tid + s]; __syncthreads(); }
  const float psum = red[0]; __syncthreads();

  float amaxl[16], aminl[16], rn[8];
#pragma unroll
  for (int n = 0; n < 16; ++n) { amaxl[n] = -1e30f; aminl[n] = 1e30f; }
#pragma unroll
  for (int j = 0; j < 8; ++j) {
    const int d = tid + (j << 8);
    float ss = 0.f;
#pragma unroll
    for (int n = 0; n < 16; ++n) {
      float a = A_log[(d << 4) + n];
      float e = __expf(a);
      ss = fmaf(e, e, ss);
      amaxl[n] = fmaxf(amaxl[n], a);
      aminl[n] = fminf(aminl[n], a);
    }
    rn[j] = sqrtf(ss);
  }
  float rm = rn[0];
#pragma unroll
  for (int j = 1; j < 8; ++j) rm = fmaxf(rm, rn[j]);
  red[tid] = rm; __syncthreads();
  for (int s = 128; s > 0; s >>= 1) { if (tid < s) red[tid] = fmaxf(red[tid], red[tid + s]); __syncthreads(); }
  const float rnmax = red[0]; __syncthreads();

#pragma unroll
  for (int n = 0; n < 16; ++n) AM[tid][n] = amaxl[n];
  __syncthreads();
  if (tid < 16) { float m = -1e30f; for (int i = 0; i < 256; ++i) m = fmaxf(m, AM[i][tid]); sAmax[tid] = m; }
  __syncthreads();
#pragma unroll
  for (int n = 0; n < 16; ++n) AM[tid][n] = aminl[n];
  __syncthreads();
  if (tid < 16) { float m = 1e30f; for (int i = 0; i < 256; ++i) m = fminf(m, AM[i][tid]); sAmin[tid] = m; }
  __syncthreads();

  const float irn = 1.f / (rnmax + 1e-8f);
#pragma unroll
  for (int j = 0; j < 8; ++j) {
    const int d = tid + (j << 8);
    const float att = rn[j] * irn;
    const float f = p[j] / psum;
    const float alpha = fminf(fmaxf(f * (1.f - att), 0.f), 1.f);
#pragma unroll
    for (int n = 0; n < 16; ++n) {
      float a = A_log[(d << 4) + n];
      float fl = sAmax[n] + sAmin[n] - a;
      float an = (1.f - alpha) * a + alpha * fl;
      Aws[(d << 4) + n] = -__expf(an);
    }
  }
}

// ---------------------------------------------------------------------------
// Depthwise causal conv (k=4) + bias + SiLU.  X (b,l,2048) -> U (b,l,2048)
// ---------------------------------------------------------------------------
__global__ __launch_bounds__(256) void conv_kernel(
    const float* __restrict__ X, const float* __restrict__ cw,
    const float* __restrict__ cb, float* __restrict__ U)
{
  const size_t idx = ((size_t)blockIdx.x << 8) + threadIdx.x;
  const int e = (int)(idx & 2047);
  const int l = (int)((idx >> 11) & 2047);
  const float* xr = X + (idx & ~(size_t)2047) + e;
  const float4 w = ((const float4*)cw)[e];
  float acc = cb[e];
  if (l >= 3) acc = fmaf(xr[-3 * 2048], w.x, acc);
  if (l >= 2) acc = fmaf(xr[-2 * 2048], w.y, acc);
  if (l >= 1) acc = fmaf(xr[-1 * 2048], w.z, acc);
  acc = fmaf(xr[0], w.w, acc);
  U[idx] = silu_(acc);
}

// ---------------------------------------------------------------------------
// Chunked selective scan (delta in X region stride 2048, z in Z stride 2048).
// ---------------------------------------------------------------------------
__global__ __launch_bounds__(256) void scan_pass1(
    const float* __restrict__ delta, const float* __restrict__ U,
    const float* __restrict__ xdbl, const float* __restrict__ Aws,
    float* __restrict__ cs, float* __restrict__ sdt)
{
  __shared__ float blds[CL * 16];
  const int tid = threadIdx.x;
  const int dg = blockIdx.x & 7;
  const int chunk = (blockIdx.x >> 3) & 31;
  const int b = blockIdx.x >> 8;
  const int d = (dg << 8) | tid;
  const int l0 = chunk * CL;

  for (int i = tid; i < CL * 16; i += 256) {
    int l = i >> 4, j = i & 15;
    blds[i] = xdbl[(size_t)(b * LSEQ + l0 + l) * 96 + 64 + j];
  }
  __syncthreads();

  float Ar[16];
#pragma unroll
  for (int n = 0; n < 16; ++n) Ar[n] = Aws[(d << 4) + n];
  float s[16];
#pragma unroll
  for (int n = 0; n < 16; ++n) s[n] = 0.f;
  float sumdt = 0.f;

  const float* dp = delta + ((size_t)b << 22) + ((size_t)l0 << 11) + d;
  const float* up = U + ((size_t)b << 22) + ((size_t)l0 << 11) + d;

  for (int l = 0; l < CL; ++l) {
    const float dt = dp[(size_t)l << 11];
    const float u = up[(size_t)l << 11];
    sumdt += dt;
    const float du = dt * u;
    const float* bl = &blds[l << 4];
#pragma unroll
    for (int n = 0; n < 16; ++n)
      s[n] = fmaf(s[n], __expf(dt * Ar[n]), du * bl[n]);
  }

  float* csp = cs + ((((size_t)b * NC + chunk) * 2048 + d) << 4);
#pragma unroll
  for (int n = 0; n < 4; ++n)
    *(float4*)(csp + (n << 2)) = make_float4(s[4*n], s[4*n+1], s[4*n+2], s[4*n+3]);
  sdt[((size_t)b * NC + chunk) * 2048 + d] = sumdt;
}

__global__ __launch_bounds__(256) void scan_mid(
    float* __restrict__ cs, const float* __restrict__ sdt,
    const float* __restrict__ Aws)
{
  const int b = blockIdx.x >> 3;
  const int d = ((blockIdx.x & 7) << 8) | threadIdx.x;
  float Ar[16];
#pragma unroll
  for (int n = 0; n < 16; ++n) Ar[n] = Aws[(d << 4) + n];
  float si[16];
#pragma unroll
  for (int n = 0; n < 16; ++n) si[n] = 0.f;

  for (int c = 0; c < NC; ++c) {
    const size_t base = ((size_t)b * NC + c) * 2048 + d;
    float* csp = cs + (base << 4);
    float sl[16];
#pragma unroll
    for (int n = 0; n < 4; ++n) {
      float4 v = *(const float4*)(csp + (n << 2));
      sl[4*n] = v.x; sl[4*n+1] = v.y; sl[4*n+2] = v.z; sl[4*n+3] = v.w;
    }
    const float sm = sdt[base];
#pragma unroll
    for (int n = 0; n < 4; ++n)
      *(float4*)(csp + (n << 2)) = make_float4(si[4*n], si[4*n+1], si[4*n+2], si[4*n+3]);
#pragma unroll
    for (int n = 0; n < 16; ++n)
      si[n] = fmaf(si[n], __expf(sm * Ar[n]), sl[n]);
  }
}

__global__ __launch_bounds__(256) void scan_pass3(
    const float* __restrict__ delta, const float* __restrict__ Z,
    float* __restrict__ U,
    const float* __restrict__ xdbl, const float* __restrict__ Aws,
    const float* __restrict__ Dp, const float* __restrict__ cs)
{
  __shared__ float bclds[CL * 32];
  const int tid = threadIdx.x;
  const int dg = blockIdx.x & 7;
  const int chunk = (blockIdx.x >> 3) & 31;
  const int b = blockIdx.x >> 8;
  const int d = (dg << 8) | tid;
  const int l0 = chunk * CL;

  for (int i = tid; i < CL * 32; i += 256) {
    int l = i >> 5, j = i & 31;
    bclds[i] = xdbl[(size_t)(b * LSEQ + l0 + l) * 96 + 64 + j];
  }
  __syncthreads();

  float Ar[16];
#pragma unroll
  for (int n = 0; n < 16; ++n) Ar[n] = Aws[(d << 4) + n];
  const float Dd = Dp[d];

  const float* csp = cs + ((((size_t)b * NC + chunk) * 2048 + d) << 4);
  float s[16];
#pragma unroll
  for (int n = 0; n < 4; ++n) {
    float4 v = *(const float4*)(csp + (n << 2));
    s[4*n] = v.x; s[4*n+1] = v.y; s[4*n+2] = v.z; s[4*n+3] = v.w;
  }

  const float* dp = delta + ((size_t)b << 22) + ((size_t)l0 << 11) + d;
  const float* zp = Z + ((size_t)b << 22) + ((size_t)l0 << 11) + d;
  float* up = U + ((size_t)b << 22) + ((size_t)l0 << 11) + d;

  for (int l = 0; l < CL; ++l) {
    const float dt = dp[(size_t)l << 11];
    const float u = up[(size_t)l << 11];
    const float z = zp[(size_t)l << 11];
    const float du = dt * u;
    const float* bcl = &bclds[l << 5];
    float y = 0.f;
#pragma unroll
    for (int n = 0; n < 16; ++n) {
      s[n] = fmaf(s[n], __expf(dt * Ar[n]), du * bcl[n]);
      y = fmaf(s[n], bcl[16 + n], y);
    }
    const float yv = fmaf(u, Dd, y);
    up[(size_t)l << 11] = yv * silu_(z);
  }
}

// ---------------------------------------------------------------------------
extern "C" void kernel_launch(void* const* d_in, const int* in_sizes, int n_in,
                              void* d_out, int out_size, void* d_ws, size_t ws_size,
                              hipStream_t stream)
{
  const float* hs         = (const float*)d_in[0];
  const float* in_proj_w  = (const float*)d_in[4];
  const float* conv_w     = (const float*)d_in[5];
  const float* conv_b     = (const float*)d_in[6];
  const float* x_proj_w   = (const float*)d_in[7];
  const float* dt_proj_w  = (const float*)d_in[8];
  const float* dt_proj_b  = (const float*)d_in[9];
  const float* A_log      = (const float*)d_in[10];
  const float* Dp         = (const float*)d_in[11];
  const float* out_proj_w = (const float*)d_in[12];
  float* out = (float*)d_out;
  float* ws = (float*)d_ws;

  float* X     = ws + OFF_X;
  float* Z     = ws + OFF_Z;
  float* U     = ws + OFF_U;
  float* cs    = ws + OFF_CS;
  float* sdt   = ws + OFF_SDT;
  float* xdbl  = ws + OFF_XDBL;
  float* feats = ws + OFF_FEAT;
  float* norms = ws + OFF_NORM;
  float* Aws   = ws + OFF_AWS;
  unsigned short* A1s = (unsigned short*)(ws + OFF_S);
  unsigned short* B1s = (unsigned short*)(ws + OFF_B1);
  unsigned short* B2s = (unsigned short*)(ws + OFF_B1);
  unsigned short* A2s = (unsigned short*)U;   // y split in place

  const dim3 blk(256);

  // 0. split hs and in_proj_w to [hi|lo] bf16
  split_w<<<32768, blk, 0, stream>>>(hs, A1s, 10);
  split_w<<<16384, blk, 0, stream>>>(in_proj_w, B1s, 10);
  // 1. xz = hs @ in_proj_w^T  (MFMA split, M=8192,N=4096,K=1024) -> X | Z
  gemm_mfma<1><<<dim3(32, 64), blk, 0, stream>>>(A1s, B1s, X, Z, 1024, 2048);
  // 2. channel-alignment features (reads X)
  feat_kernel<<<4096, blk, 0, stream>>>(X, feats);
  // 3. depthwise conv + silu (X -> U)
  conv_kernel<<<65536, blk, 0, stream>>>(X, conv_w, conv_b, U);
  // 3b. split out_proj_w (overlays dead B1s region)
  split_w<<<8192, blk, 0, stream>>>(out_proj_w, B2s, 11);
  // 4. per-frame feature norms
  norms_kernel<<<32, blk, 0, stream>>>(feats, norms);
  // 5. loss + alpha + A
  alpha_kernel<<<1, blk, 0, stream>>>(feats, norms, A_log, Aws, out + 8388608);
  // 6. x_dbl = U @ x_proj_w^T   (M=8192, N=96, K=2048)
  gemm_nt<0><<<dim3(2, 128), blk, 0, stream>>>(U, DI, x_proj_w, DI, xdbl, 96, 96, DI, nullptr);
  // 7. delta = softplus(x_dbl[:, :64] @ dt_proj_w^T + b) -> X region (dead x)
  gemm_nt<1><<<dim3(32, 128), blk, 0, stream>>>(xdbl, 96, dt_proj_w, 64, X, DI, DI, 64, dt_proj_b);
  // 8. chunked selective scan; y overwrites U (fp32)
  scan_pass1<<<1024, blk, 0, stream>>>(X, U, xdbl, Aws, cs, sdt);
  scan_mid<<<32, blk, 0, stream>>>(cs, sdt, Aws);
  scan_pass3<<<1024, blk, 0, stream>>>(X, Z, U, xdbl, Aws, Dp, cs);
  // 9. in-place split y -> bf16 [hi|lo]
  split_inplace<<<8192, blk, 0, stream>>>(U);
  // 10. out = y @ out_proj_w^T  (MFMA split, M=8192,N=1024,K=2048)
  gemm_mfma<0><<<dim3(8, 64), blk, 0, stream>>>(A2s, B2s, out, nullptr, 2048, 1024);
}